// Round 1
// baseline (1382.905 us; speedup 1.0000x reference)
//
#include <hip/hip_runtime.h>
#include <math.h>

#define NT 100000
#define ET 1600000
#define GT 128

// ---------------- workspace layout (bytes) ----------------
// row_ptr : 0          (N+1)*4
// cursor  : 400128     N*4          (also used as counts)
// partials: 800256     512
// adj     : 800768     E*4
// es1     : 7200768    N*4*4
// ed1     : 8800768    N*4*4
// es2     : 10400768   N*4
// ed2     : 10800768   N*4
// psum    : 11200768   G*32*4
// pcnt    : 11217152   512
// h1      : 11217664   N*128*4
// h1out   : 62417664   N*128*4
// h2      : alias h1
// h2out   : 24017664   N*32*4   (inside dead h1 region)

__device__ __forceinline__ float lrelu(float v) { return v > 0.0f ? v : 0.2f * v; }

// ---------------- CSR build ----------------
__global__ void k_count(const int* __restrict__ dst, int* __restrict__ counts) {
  int e = blockIdx.x * 256 + threadIdx.x;
  if (e < ET) atomicAdd(&counts[dst[e]], 1);
}

__global__ __launch_bounds__(256) void k_scan1(const int* __restrict__ counts,
                                               int* __restrict__ scanned,
                                               int* __restrict__ partials) {
  __shared__ int sh[256];
  int t = threadIdx.x;
  int base = blockIdx.x * 1024 + t * 4;
  int v[4];
#pragma unroll
  for (int i = 0; i < 4; ++i) v[i] = (base + i < NT) ? counts[base + i] : 0;
  int tsum = v[0] + v[1] + v[2] + v[3];
  sh[t] = tsum;
  __syncthreads();
  for (int off = 1; off < 256; off <<= 1) {
    int xv = (t >= off) ? sh[t - off] : 0;
    __syncthreads();
    sh[t] += xv;
    __syncthreads();
  }
  int ex = sh[t] - tsum;
#pragma unroll
  for (int i = 0; i < 4; ++i) {
    if (base + i < NT) scanned[base + i] = ex;
    ex += v[i];
  }
  if (t == 255) partials[blockIdx.x] = sh[255];
}

__global__ void k_scan2(int* partials) {
  if (threadIdx.x == 0) {
    int s = 0;
    for (int i = 0; i < 98; ++i) { int v = partials[i]; partials[i] = s; s += v; }
    partials[98] = s;
  }
}

__global__ void k_scan3(int* __restrict__ rp, int* __restrict__ cursor,
                        const int* __restrict__ partials) {
  int i = blockIdx.x * 256 + threadIdx.x;
  if (i < NT) {
    int v = rp[i] + partials[i >> 10];
    rp[i] = v;
    cursor[i] = v;
    if (i == 0) rp[NT] = ET;
  }
}

__global__ void k_scatter(const int* __restrict__ src, const int* __restrict__ dst,
                          int* __restrict__ cursor, int* __restrict__ adj) {
  int e = blockIdx.x * 256 + threadIdx.x;
  if (e < ET) {
    int pos = atomicAdd(&cursor[dst[e]], 1);
    adj[pos] = src[e];
  }
}

// ---------------- GEMM1: h1 = x @ W1 (N x 32 -> N x 128), fused e_src/e_dst ----------------
__global__ __launch_bounds__(256) void k_gemm1(const float* __restrict__ x, const float* __restrict__ W,
                                               const float* __restrict__ asrc, const float* __restrict__ adst,
                                               float* __restrict__ h, float* __restrict__ es,
                                               float* __restrict__ ed) {
  __shared__ float Wsh[32 * 128];
  __shared__ float xT[32 * 72];  // stride 72 to spread banks, keep 16B align
  int tid = threadIdx.x;
  int node0 = blockIdx.x * 64;
  for (int i = tid; i < 4096; i += 256) Wsh[i] = W[i];
  for (int i = tid; i < 2048; i += 256) {
    int ln = i >> 5, k = i & 31;
    int node = node0 + ln;
    xT[k * 72 + ln] = (node < NT) ? x[node * 32 + k] : 0.0f;
  }
  __syncthreads();
  int cg = tid & 15, ng = tid >> 4;
  int c0 = cg * 8, n0 = ng * 4;
  float acc[4][8];
#pragma unroll
  for (int i = 0; i < 4; ++i)
#pragma unroll
    for (int j = 0; j < 8; ++j) acc[i][j] = 0.0f;
#pragma unroll
  for (int k = 0; k < 32; ++k) {
    float4 xv = *(const float4*)&xT[k * 72 + n0];
    float4 wa = *(const float4*)&Wsh[k * 128 + c0];
    float4 wb = *(const float4*)&Wsh[k * 128 + c0 + 4];
    float xs[4] = {xv.x, xv.y, xv.z, xv.w};
    float wv[8] = {wa.x, wa.y, wa.z, wa.w, wb.x, wb.y, wb.z, wb.w};
#pragma unroll
    for (int i = 0; i < 4; ++i)
#pragma unroll
      for (int j = 0; j < 8; ++j) acc[i][j] += xs[i] * wv[j];
  }
  int head = cg >> 2;
  float ps[4], pd[4];
#pragma unroll
  for (int i = 0; i < 4; ++i) {
    float s = 0.0f, d = 0.0f;
#pragma unroll
    for (int j = 0; j < 8; ++j) {
      s += acc[i][j] * asrc[c0 + j];
      d += acc[i][j] * adst[c0 + j];
    }
    ps[i] = s; pd[i] = d;
  }
#pragma unroll
  for (int off = 1; off < 4; off <<= 1) {
#pragma unroll
    for (int i = 0; i < 4; ++i) {
      ps[i] += __shfl_xor(ps[i], off);
      pd[i] += __shfl_xor(pd[i], off);
    }
  }
#pragma unroll
  for (int i = 0; i < 4; ++i) {
    int node = node0 + n0 + i;
    if (node < NT) {
      float4 o0 = make_float4(acc[i][0], acc[i][1], acc[i][2], acc[i][3]);
      float4 o1 = make_float4(acc[i][4], acc[i][5], acc[i][6], acc[i][7]);
      *(float4*)&h[node * 128 + c0] = o0;
      *(float4*)&h[node * 128 + c0 + 4] = o1;
      if ((cg & 3) == 0) {
        es[node * 4 + head] = ps[i];
        ed[node * 4 + head] = pd[i];
      }
    }
  }
}

// ---------------- agg1: per-node softmax + aggregate, heads=4, ch=32 ----------------
__global__ __launch_bounds__(128) void k_agg1(const int* __restrict__ rp, const int* __restrict__ adj,
                                              const float* __restrict__ es, const float* __restrict__ ed,
                                              const float* __restrict__ h, const float* __restrict__ b1,
                                              float* __restrict__ out) {
  int n = blockIdx.x;
  int tid = threadIdx.x;
  int head = tid >> 5;
  int rs = rp[n], re = rp[n + 1];
  float edst = ed[n * 4 + head];
  float vs = lrelu(es[n * 4 + head] + edst);  // self-loop
  float m = vs, den = 1.0f;
  for (int j = rs; j < re; ++j) {
    int s = adj[j];
    float v = lrelu(es[s * 4 + head] + edst);
    if (v > m) { den = den * expf(m - v) + 1.0f; m = v; }
    else den += expf(v - m);
  }
  float inv = 1.0f / den;
  float acc = expf(vs - m) * inv * h[n * 128 + tid];
  for (int j = rs; j < re; ++j) {
    int s = adj[j];
    float v = lrelu(es[s * 4 + head] + edst);
    acc += expf(v - m) * inv * h[s * 128 + tid];
  }
  float o = acc + b1[tid];
  out[n * 128 + tid] = o > 0.0f ? o : expm1f(o);
}

// ---------------- GEMM2: h2 = h1out @ W2 (N x 128 -> N x 32), fused e_src/e_dst ----------------
__global__ __launch_bounds__(256) void k_gemm2(const float* __restrict__ hin, const float* __restrict__ W,
                                               const float* __restrict__ asrc, const float* __restrict__ adst,
                                               float* __restrict__ h2, float* __restrict__ es,
                                               float* __restrict__ ed) {
  __shared__ float Wsh[128 * 32];
  __shared__ float hT[128 * 72];
  int tid = threadIdx.x;
  int node0 = blockIdx.x * 64;
  for (int i = tid; i < 4096; i += 256) Wsh[i] = W[i];
  for (int i = tid; i < 8192; i += 256) {
    int ln = i >> 7, k = i & 127;
    int node = node0 + ln;
    hT[k * 72 + ln] = (node < NT) ? hin[node * 128 + k] : 0.0f;
  }
  __syncthreads();
  int cg = tid & 15, ng = tid >> 4;
  int c0 = cg * 2, n0 = ng * 4;
  float acc[4][2] = {{0.0f, 0.0f}, {0.0f, 0.0f}, {0.0f, 0.0f}, {0.0f, 0.0f}};
#pragma unroll 8
  for (int k = 0; k < 128; ++k) {
    float4 xv = *(const float4*)&hT[k * 72 + n0];
    float2 wv = *(const float2*)&Wsh[k * 32 + c0];
    acc[0][0] += xv.x * wv.x; acc[0][1] += xv.x * wv.y;
    acc[1][0] += xv.y * wv.x; acc[1][1] += xv.y * wv.y;
    acc[2][0] += xv.z * wv.x; acc[2][1] += xv.z * wv.y;
    acc[3][0] += xv.w * wv.x; acc[3][1] += xv.w * wv.y;
  }
  float ps[4], pd[4];
#pragma unroll
  for (int i = 0; i < 4; ++i) {
    ps[i] = acc[i][0] * asrc[c0] + acc[i][1] * asrc[c0 + 1];
    pd[i] = acc[i][0] * adst[c0] + acc[i][1] * adst[c0 + 1];
  }
#pragma unroll
  for (int off = 1; off < 16; off <<= 1) {
#pragma unroll
    for (int i = 0; i < 4; ++i) {
      ps[i] += __shfl_xor(ps[i], off);
      pd[i] += __shfl_xor(pd[i], off);
    }
  }
#pragma unroll
  for (int i = 0; i < 4; ++i) {
    int node = node0 + n0 + i;
    if (node < NT) {
      *(float2*)&h2[node * 32 + c0] = make_float2(acc[i][0], acc[i][1]);
      if (cg == 0) { es[node] = ps[i]; ed[node] = pd[i]; }
    }
  }
}

// ---------------- agg2: per-node softmax + aggregate, heads=1, ch=32 ----------------
__global__ __launch_bounds__(128) void k_agg2(const int* __restrict__ rp, const int* __restrict__ adj,
                                              const float* __restrict__ es, const float* __restrict__ ed,
                                              const float* __restrict__ h, const float* __restrict__ b2,
                                              float* __restrict__ out) {
  int grp = threadIdx.x >> 5, c = threadIdx.x & 31;
  int n = blockIdx.x * 4 + grp;
  if (n >= NT) return;
  int rs = rp[n], re = rp[n + 1];
  float edst = ed[n];
  float vs = lrelu(es[n] + edst);
  float m = vs, den = 1.0f;
  for (int j = rs; j < re; ++j) {
    int s = adj[j];
    float v = lrelu(es[s] + edst);
    if (v > m) { den = den * expf(m - v) + 1.0f; m = v; }
    else den += expf(v - m);
  }
  float inv = 1.0f / den;
  float acc = expf(vs - m) * inv * h[n * 32 + c];
  for (int j = rs; j < re; ++j) {
    int s = adj[j];
    float v = lrelu(es[s] + edst);
    acc += expf(v - m) * inv * h[s * 32 + c];
  }
  float o = acc + b2[c];
  out[n * 32 + c] = o > 0.0f ? o : expm1f(o);
}

// ---------------- pooling + classifier ----------------
__global__ void k_pool(const float* __restrict__ h, const int* __restrict__ batch,
                       float* __restrict__ psum, float* __restrict__ pcnt) {
  int idx = blockIdx.x * 256 + threadIdx.x;
  if (idx < NT * 32) {
    int n = idx >> 5, c = idx & 31;
    int g = batch[n];
    atomicAdd(&psum[g * 32 + c], h[idx]);
    if (c == 0) atomicAdd(&pcnt[g], 1.0f);
  }
}

__global__ void k_final(const float* __restrict__ psum, const float* __restrict__ pcnt,
                        const float* __restrict__ Wc, const float* __restrict__ bc,
                        float* __restrict__ out) {
  int g = threadIdx.x;
  if (g < GT) {
    float cnt = pcnt[g];
    float inv = 1.0f / (cnt > 1.0f ? cnt : 1.0f);
    float acc = 0.0f;
    for (int c = 0; c < 32; ++c) acc += psum[g * 32 + c] * inv * Wc[c];
    out[g] = acc + bc[0];
  }
}

extern "C" void kernel_launch(void* const* d_in, const int* in_sizes, int n_in,
                              void* d_out, int out_size, void* d_ws, size_t ws_size,
                              hipStream_t stream) {
  const float* x = (const float*)d_in[0];
  const int* ei = (const int*)d_in[1];
  const int* src = ei;
  const int* dst = ei + ET;
  const int* batch = (const int*)d_in[2];
  const float* W1 = (const float*)d_in[3];
  const float* asrc1 = (const float*)d_in[4];
  const float* adst1 = (const float*)d_in[5];
  const float* b1 = (const float*)d_in[6];
  const float* W2 = (const float*)d_in[7];
  const float* asrc2 = (const float*)d_in[8];
  const float* adst2 = (const float*)d_in[9];
  const float* b2 = (const float*)d_in[10];
  const float* Wc = (const float*)d_in[11];
  const float* bc = (const float*)d_in[12];
  float* out = (float*)d_out;
  char* ws = (char*)d_ws;

  int* row_ptr = (int*)(ws + 0);
  int* cursor = (int*)(ws + 400128);
  int* partials = (int*)(ws + 800256);
  int* adj = (int*)(ws + 800768);
  float* es1 = (float*)(ws + 7200768);
  float* ed1 = (float*)(ws + 8800768);
  float* es2 = (float*)(ws + 10400768);
  float* ed2 = (float*)(ws + 10800768);
  float* psum = (float*)(ws + 11200768);
  float* pcnt = (float*)(ws + 11217152);
  float* h1 = (float*)(ws + 11217664);
  float* h1o = (float*)(ws + 62417664);
  float* h2 = h1;                        // h1 dead after agg1
  float* h2o = (float*)(ws + 24017664);  // inside dead h1 region

  // zero accumulators (counts + pool)
  hipMemsetAsync(cursor, 0, NT * 4, stream);
  hipMemsetAsync(psum, 0, 16384 + 512, stream);

  // CSR build (shared by both layers)
  k_count<<<(ET + 255) / 256, 256, 0, stream>>>(dst, cursor);
  k_scan1<<<98, 256, 0, stream>>>(cursor, row_ptr, partials);
  k_scan2<<<1, 64, 0, stream>>>(partials);
  k_scan3<<<(NT + 255) / 256, 256, 0, stream>>>(row_ptr, cursor, partials);
  k_scatter<<<(ET + 255) / 256, 256, 0, stream>>>(src, dst, cursor, adj);

  // layer 1
  k_gemm1<<<(NT + 63) / 64, 256, 0, stream>>>(x, W1, asrc1, adst1, h1, es1, ed1);
  k_agg1<<<NT, 128, 0, stream>>>(row_ptr, adj, es1, ed1, h1, b1, h1o);

  // layer 2
  k_gemm2<<<(NT + 63) / 64, 256, 0, stream>>>(h1o, W2, asrc2, adst2, h2, es2, ed2);
  k_agg2<<<(NT + 3) / 4, 128, 0, stream>>>(row_ptr, adj, es2, ed2, h2, b2, h2o);

  // pool + classify
  k_pool<<<(NT * 32 + 255) / 256, 256, 0, stream>>>(h2o, batch, psum, pcnt);
  k_final<<<1, 128, 0, stream>>>(psum, pcnt, Wc, bc, out);
}

// Round 2
// 843.893 us; speedup vs baseline: 1.6387x; 1.6387x over previous
//
#include <hip/hip_runtime.h>
#include <math.h>

#define NT 100000
#define ET 1600000
#define GT 128

// ---------------- workspace layout (bytes) ----------------
// row_ptr : 0          (N+1)*4
// cursor  : 400128     N*4          (also used as counts)
// partials: 800256     512
// adj     : 800768     E*4
// es1     : 7200768    N*4*4
// ed1     : 8800768    N*4*4
// es2     : 10400768   N*4
// ed2     : 10800768   N*4
// h1      : 11217664   N*128*4
// h1out   : 62417664   N*128*4
// h2      : alias h1
// h2out   : 24017664   N*32*4   (inside dead h1 region)

__device__ __forceinline__ float lrelu(float v) { return v > 0.0f ? v : 0.2f * v; }

// ---------------- CSR build ----------------
__global__ void k_count(const int* __restrict__ dst, int* __restrict__ counts) {
  int e = blockIdx.x * 256 + threadIdx.x;
  if (e < ET) atomicAdd(&counts[dst[e]], 1);
}

__global__ __launch_bounds__(256) void k_scan1(const int* __restrict__ counts,
                                               int* __restrict__ scanned,
                                               int* __restrict__ partials) {
  __shared__ int sh[256];
  int t = threadIdx.x;
  int base = blockIdx.x * 1024 + t * 4;
  int v[4];
#pragma unroll
  for (int i = 0; i < 4; ++i) v[i] = (base + i < NT) ? counts[base + i] : 0;
  int tsum = v[0] + v[1] + v[2] + v[3];
  sh[t] = tsum;
  __syncthreads();
  for (int off = 1; off < 256; off <<= 1) {
    int xv = (t >= off) ? sh[t - off] : 0;
    __syncthreads();
    sh[t] += xv;
    __syncthreads();
  }
  int ex = sh[t] - tsum;
#pragma unroll
  for (int i = 0; i < 4; ++i) {
    if (base + i < NT) scanned[base + i] = ex;
    ex += v[i];
  }
  if (t == 255) partials[blockIdx.x] = sh[255];
}

__global__ void k_scan2(int* partials) {
  if (threadIdx.x == 0) {
    int s = 0;
    for (int i = 0; i < 98; ++i) { int v = partials[i]; partials[i] = s; s += v; }
    partials[98] = s;
  }
}

__global__ void k_scan3(int* __restrict__ rp, int* __restrict__ cursor,
                        const int* __restrict__ partials) {
  int i = blockIdx.x * 256 + threadIdx.x;
  if (i < NT) {
    int v = rp[i] + partials[i >> 10];
    rp[i] = v;
    cursor[i] = v;
    if (i == 0) rp[NT] = ET;
  }
}

__global__ void k_scatter(const int* __restrict__ src, const int* __restrict__ dst,
                          int* __restrict__ cursor, int* __restrict__ adj) {
  int e = blockIdx.x * 256 + threadIdx.x;
  if (e < ET) {
    int pos = atomicAdd(&cursor[dst[e]], 1);
    adj[pos] = src[e];
  }
}

// ---------------- GEMM1: h1 = x @ W1 (N x 32 -> N x 128), fused e_src/e_dst ----------------
__global__ __launch_bounds__(256) void k_gemm1(const float* __restrict__ x, const float* __restrict__ W,
                                               const float* __restrict__ asrc, const float* __restrict__ adst,
                                               float* __restrict__ h, float* __restrict__ es,
                                               float* __restrict__ ed) {
  __shared__ float Wsh[32 * 128];
  __shared__ float xT[32 * 72];  // stride 72 to spread banks, keep 16B align
  int tid = threadIdx.x;
  int node0 = blockIdx.x * 64;
  for (int i = tid; i < 4096; i += 256) Wsh[i] = W[i];
  for (int i = tid; i < 2048; i += 256) {
    int ln = i >> 5, k = i & 31;
    int node = node0 + ln;
    xT[k * 72 + ln] = (node < NT) ? x[node * 32 + k] : 0.0f;
  }
  __syncthreads();
  int cg = tid & 15, ng = tid >> 4;
  int c0 = cg * 8, n0 = ng * 4;
  float acc[4][8];
#pragma unroll
  for (int i = 0; i < 4; ++i)
#pragma unroll
    for (int j = 0; j < 8; ++j) acc[i][j] = 0.0f;
#pragma unroll
  for (int k = 0; k < 32; ++k) {
    float4 xv = *(const float4*)&xT[k * 72 + n0];
    float4 wa = *(const float4*)&Wsh[k * 128 + c0];
    float4 wb = *(const float4*)&Wsh[k * 128 + c0 + 4];
    float xs[4] = {xv.x, xv.y, xv.z, xv.w};
    float wv[8] = {wa.x, wa.y, wa.z, wa.w, wb.x, wb.y, wb.z, wb.w};
#pragma unroll
    for (int i = 0; i < 4; ++i)
#pragma unroll
      for (int j = 0; j < 8; ++j) acc[i][j] += xs[i] * wv[j];
  }
  int head = cg >> 2;
  float ps[4], pd[4];
#pragma unroll
  for (int i = 0; i < 4; ++i) {
    float s = 0.0f, d = 0.0f;
#pragma unroll
    for (int j = 0; j < 8; ++j) {
      s += acc[i][j] * asrc[c0 + j];
      d += acc[i][j] * adst[c0 + j];
    }
    ps[i] = s; pd[i] = d;
  }
#pragma unroll
  for (int off = 1; off < 4; off <<= 1) {
#pragma unroll
    for (int i = 0; i < 4; ++i) {
      ps[i] += __shfl_xor(ps[i], off);
      pd[i] += __shfl_xor(pd[i], off);
    }
  }
#pragma unroll
  for (int i = 0; i < 4; ++i) {
    int node = node0 + n0 + i;
    if (node < NT) {
      float4 o0 = make_float4(acc[i][0], acc[i][1], acc[i][2], acc[i][3]);
      float4 o1 = make_float4(acc[i][4], acc[i][5], acc[i][6], acc[i][7]);
      *(float4*)&h[node * 128 + c0] = o0;
      *(float4*)&h[node * 128 + c0 + 4] = o1;
      if ((cg & 3) == 0) {
        es[node * 4 + head] = ps[i];
        ed[node * 4 + head] = pd[i];
      }
    }
  }
}

// ---------------- agg1: per-node softmax + aggregate, heads=4, ch=32 ----------------
__global__ __launch_bounds__(128) void k_agg1(const int* __restrict__ rp, const int* __restrict__ adj,
                                              const float* __restrict__ es, const float* __restrict__ ed,
                                              const float* __restrict__ h, const float* __restrict__ b1,
                                              float* __restrict__ out) {
  int n = blockIdx.x;
  int tid = threadIdx.x;
  int head = tid >> 5;
  int rs = rp[n], re = rp[n + 1];
  float edst = ed[n * 4 + head];
  float vs = lrelu(es[n * 4 + head] + edst);  // self-loop
  float m = vs, den = 1.0f;
  for (int j = rs; j < re; ++j) {
    int s = adj[j];
    float v = lrelu(es[s * 4 + head] + edst);
    if (v > m) { den = den * expf(m - v) + 1.0f; m = v; }
    else den += expf(v - m);
  }
  float inv = 1.0f / den;
  float acc = expf(vs - m) * inv * h[n * 128 + tid];
  for (int j = rs; j < re; ++j) {
    int s = adj[j];
    float v = lrelu(es[s * 4 + head] + edst);
    acc += expf(v - m) * inv * h[s * 128 + tid];
  }
  float o = acc + b1[tid];
  out[n * 128 + tid] = o > 0.0f ? o : expm1f(o);
}

// ---------------- GEMM2: h2 = h1out @ W2 (N x 128 -> N x 32), fused e_src/e_dst ----------------
__global__ __launch_bounds__(256) void k_gemm2(const float* __restrict__ hin, const float* __restrict__ W,
                                               const float* __restrict__ asrc, const float* __restrict__ adst,
                                               float* __restrict__ h2, float* __restrict__ es,
                                               float* __restrict__ ed) {
  __shared__ float Wsh[128 * 32];
  __shared__ float hT[128 * 72];
  int tid = threadIdx.x;
  int node0 = blockIdx.x * 64;
  for (int i = tid; i < 4096; i += 256) Wsh[i] = W[i];
  for (int i = tid; i < 8192; i += 256) {
    int ln = i >> 7, k = i & 127;
    int node = node0 + ln;
    hT[k * 72 + ln] = (node < NT) ? hin[node * 128 + k] : 0.0f;
  }
  __syncthreads();
  int cg = tid & 15, ng = tid >> 4;
  int c0 = cg * 2, n0 = ng * 4;
  float acc[4][2] = {{0.0f, 0.0f}, {0.0f, 0.0f}, {0.0f, 0.0f}, {0.0f, 0.0f}};
#pragma unroll 8
  for (int k = 0; k < 128; ++k) {
    float4 xv = *(const float4*)&hT[k * 72 + n0];
    float2 wv = *(const float2*)&Wsh[k * 32 + c0];
    acc[0][0] += xv.x * wv.x; acc[0][1] += xv.x * wv.y;
    acc[1][0] += xv.y * wv.x; acc[1][1] += xv.y * wv.y;
    acc[2][0] += xv.z * wv.x; acc[2][1] += xv.z * wv.y;
    acc[3][0] += xv.w * wv.x; acc[3][1] += xv.w * wv.y;
  }
  float ps[4], pd[4];
#pragma unroll
  for (int i = 0; i < 4; ++i) {
    ps[i] = acc[i][0] * asrc[c0] + acc[i][1] * asrc[c0 + 1];
    pd[i] = acc[i][0] * adst[c0] + acc[i][1] * adst[c0 + 1];
  }
#pragma unroll
  for (int off = 1; off < 16; off <<= 1) {
#pragma unroll
    for (int i = 0; i < 4; ++i) {
      ps[i] += __shfl_xor(ps[i], off);
      pd[i] += __shfl_xor(pd[i], off);
    }
  }
#pragma unroll
  for (int i = 0; i < 4; ++i) {
    int node = node0 + n0 + i;
    if (node < NT) {
      *(float2*)&h2[node * 32 + c0] = make_float2(acc[i][0], acc[i][1]);
      if (cg == 0) { es[node] = ps[i]; ed[node] = pd[i]; }
    }
  }
}

// ---------------- agg2: per-node softmax + aggregate, heads=1, ch=32 ----------------
__global__ __launch_bounds__(128) void k_agg2(const int* __restrict__ rp, const int* __restrict__ adj,
                                              const float* __restrict__ es, const float* __restrict__ ed,
                                              const float* __restrict__ h, const float* __restrict__ b2,
                                              float* __restrict__ out) {
  int grp = threadIdx.x >> 5, c = threadIdx.x & 31;
  int n = blockIdx.x * 4 + grp;
  if (n >= NT) return;
  int rs = rp[n], re = rp[n + 1];
  float edst = ed[n];
  float vs = lrelu(es[n] + edst);
  float m = vs, den = 1.0f;
  for (int j = rs; j < re; ++j) {
    int s = adj[j];
    float v = lrelu(es[s] + edst);
    if (v > m) { den = den * expf(m - v) + 1.0f; m = v; }
    else den += expf(v - m);
  }
  float inv = 1.0f / den;
  float acc = expf(vs - m) * inv * h[n * 32 + c];
  for (int j = rs; j < re; ++j) {
    int s = adj[j];
    float v = lrelu(es[s] + edst);
    acc += expf(v - m) * inv * h[s * 32 + c];
  }
  float o = acc + b2[c];
  out[n * 32 + c] = o > 0.0f ? o : expm1f(o);
}

// ---------------- pooling + classifier: one block per graph, zero atomics ----------------
__global__ __launch_bounds__(256) void k_pool2(const float* __restrict__ h, const int* __restrict__ batch,
                                               const float* __restrict__ Wc, const float* __restrict__ bc,
                                               float* __restrict__ out) {
  int g = blockIdx.x;
  // first index with batch[i] >= g
  int lo = 0, hi = NT;
  while (lo < hi) { int mid = (lo + hi) >> 1; if (batch[mid] < g) lo = mid + 1; else hi = mid; }
  int start = lo;
  // first index with batch[i] >= g+1
  hi = NT;
  while (lo < hi) { int mid = (lo + hi) >> 1; if (batch[mid] < g + 1) lo = mid + 1; else hi = mid; }
  int end = lo;

  int t = threadIdx.x, c = t & 31, r = t >> 5;
  float acc = 0.0f;
  for (int n = start + r; n < end; n += 8) acc += h[n * 32 + c];
  __shared__ float sh[256];
  sh[t] = acc;
  __syncthreads();
  if (r == 0) {
    float s = 0.0f;
#pragma unroll
    for (int i = 0; i < 8; ++i) s += sh[i * 32 + c];
    float cnt = (float)(end - start);
    float inv = 1.0f / fmaxf(cnt, 1.0f);
    float v = s * inv * Wc[c];
#pragma unroll
    for (int off = 16; off >= 1; off >>= 1) v += __shfl_xor(v, off);
    if (c == 0) out[g] = v + bc[0];
  }
}

extern "C" void kernel_launch(void* const* d_in, const int* in_sizes, int n_in,
                              void* d_out, int out_size, void* d_ws, size_t ws_size,
                              hipStream_t stream) {
  const float* x = (const float*)d_in[0];
  const int* ei = (const int*)d_in[1];
  const int* src = ei;
  const int* dst = ei + ET;
  const int* batch = (const int*)d_in[2];
  const float* W1 = (const float*)d_in[3];
  const float* asrc1 = (const float*)d_in[4];
  const float* adst1 = (const float*)d_in[5];
  const float* b1 = (const float*)d_in[6];
  const float* W2 = (const float*)d_in[7];
  const float* asrc2 = (const float*)d_in[8];
  const float* adst2 = (const float*)d_in[9];
  const float* b2 = (const float*)d_in[10];
  const float* Wc = (const float*)d_in[11];
  const float* bc = (const float*)d_in[12];
  float* out = (float*)d_out;
  char* ws = (char*)d_ws;

  int* row_ptr = (int*)(ws + 0);
  int* cursor = (int*)(ws + 400128);
  int* partials = (int*)(ws + 800256);
  int* adj = (int*)(ws + 800768);
  float* es1 = (float*)(ws + 7200768);
  float* ed1 = (float*)(ws + 8800768);
  float* es2 = (float*)(ws + 10400768);
  float* ed2 = (float*)(ws + 10800768);
  float* h1 = (float*)(ws + 11217664);
  float* h1o = (float*)(ws + 62417664);
  float* h2 = h1;                        // h1 dead after agg1
  float* h2o = (float*)(ws + 24017664);  // inside dead h1 region

  // zero edge counts
  hipMemsetAsync(cursor, 0, NT * 4, stream);

  // CSR build (shared by both layers)
  k_count<<<(ET + 255) / 256, 256, 0, stream>>>(dst, cursor);
  k_scan1<<<98, 256, 0, stream>>>(cursor, row_ptr, partials);
  k_scan2<<<1, 64, 0, stream>>>(partials);
  k_scan3<<<(NT + 255) / 256, 256, 0, stream>>>(row_ptr, cursor, partials);
  k_scatter<<<(ET + 255) / 256, 256, 0, stream>>>(src, dst, cursor, adj);

  // layer 1
  k_gemm1<<<(NT + 63) / 64, 256, 0, stream>>>(x, W1, asrc1, adst1, h1, es1, ed1);
  k_agg1<<<NT, 128, 0, stream>>>(row_ptr, adj, es1, ed1, h1, b1, h1o);

  // layer 2
  k_gemm2<<<(NT + 63) / 64, 256, 0, stream>>>(h1o, W2, asrc2, adst2, h2, es2, ed2);
  k_agg2<<<(NT + 3) / 4, 128, 0, stream>>>(row_ptr, adj, es2, ed2, h2, b2, h2o);

  // pool + classify (no atomics: batch is sorted, binary-search graph ranges)
  k_pool2<<<GT, 256, 0, stream>>>(h2o, batch, Wc, bc, out);
}

// Round 3
// 558.584 us; speedup vs baseline: 2.4757x; 1.5108x over previous
//
#include <hip/hip_runtime.h>
#include <math.h>

#define NT 100000
#define ET 1600000
#define GT 128

// ---------------- workspace layout (bytes) ----------------
// row_ptr : 0          (N+1)*4
// cursor  : 400128     N*4          (also used as counts)
// partials: 800256     512
// adj     : 800768     E*4
// es1     : 7200768    N*4*4
// ed1     : 8800768    N*4*4
// es2     : 10400768   N*4
// ed2     : 10800768   N*4
// h1      : 11217664   N*128*4
// h1out   : 62417664   N*128*4
// h2      : alias h1
// h2out   : 24017664   N*32*4   (inside dead h1 region)

__device__ __forceinline__ float lrelu(float v) { return v > 0.0f ? v : 0.2f * v; }

// ---------------- CSR build ----------------
__global__ void k_count(const int* __restrict__ dst, int* __restrict__ counts) {
  int e = blockIdx.x * 256 + threadIdx.x;
  if (e < ET) atomicAdd(&counts[dst[e]], 1);
}

__global__ __launch_bounds__(256) void k_scan1(const int* __restrict__ counts,
                                               int* __restrict__ scanned,
                                               int* __restrict__ partials) {
  __shared__ int sh[256];
  int t = threadIdx.x;
  int base = blockIdx.x * 1024 + t * 4;
  int v[4];
#pragma unroll
  for (int i = 0; i < 4; ++i) v[i] = (base + i < NT) ? counts[base + i] : 0;
  int tsum = v[0] + v[1] + v[2] + v[3];
  sh[t] = tsum;
  __syncthreads();
  for (int off = 1; off < 256; off <<= 1) {
    int xv = (t >= off) ? sh[t - off] : 0;
    __syncthreads();
    sh[t] += xv;
    __syncthreads();
  }
  int ex = sh[t] - tsum;
#pragma unroll
  for (int i = 0; i < 4; ++i) {
    if (base + i < NT) scanned[base + i] = ex;
    ex += v[i];
  }
  if (t == 255) partials[blockIdx.x] = sh[255];
}

__global__ void k_scan2(int* partials) {
  if (threadIdx.x == 0) {
    int s = 0;
    for (int i = 0; i < 98; ++i) { int v = partials[i]; partials[i] = s; s += v; }
    partials[98] = s;
  }
}

__global__ void k_scan3(int* __restrict__ rp, int* __restrict__ cursor,
                        const int* __restrict__ partials) {
  int i = blockIdx.x * 256 + threadIdx.x;
  if (i < NT) {
    int v = rp[i] + partials[i >> 10];
    rp[i] = v;
    cursor[i] = v;
    if (i == 0) rp[NT] = ET;
  }
}

__global__ void k_scatter(const int* __restrict__ src, const int* __restrict__ dst,
                          int* __restrict__ cursor, int* __restrict__ adj) {
  int e = blockIdx.x * 256 + threadIdx.x;
  if (e < ET) {
    int pos = atomicAdd(&cursor[dst[e]], 1);
    adj[pos] = src[e];
  }
}

// ---------------- GEMM1: h1 = x @ W1 (N x 32 -> N x 128), fused e_src/e_dst ----------------
__global__ __launch_bounds__(256) void k_gemm1(const float* __restrict__ x, const float* __restrict__ W,
                                               const float* __restrict__ asrc, const float* __restrict__ adst,
                                               float* __restrict__ h, float* __restrict__ es,
                                               float* __restrict__ ed) {
  __shared__ float Wsh[32 * 128];
  __shared__ float xT[32 * 72];  // stride 72 to spread banks, keep 16B align
  int tid = threadIdx.x;
  int node0 = blockIdx.x * 64;
  for (int i = tid; i < 4096; i += 256) Wsh[i] = W[i];
  for (int i = tid; i < 2048; i += 256) {
    int ln = i >> 5, k = i & 31;
    int node = node0 + ln;
    xT[k * 72 + ln] = (node < NT) ? x[node * 32 + k] : 0.0f;
  }
  __syncthreads();
  int cg = tid & 15, ng = tid >> 4;
  int c0 = cg * 8, n0 = ng * 4;
  float acc[4][8];
#pragma unroll
  for (int i = 0; i < 4; ++i)
#pragma unroll
    for (int j = 0; j < 8; ++j) acc[i][j] = 0.0f;
#pragma unroll
  for (int k = 0; k < 32; ++k) {
    float4 xv = *(const float4*)&xT[k * 72 + n0];
    float4 wa = *(const float4*)&Wsh[k * 128 + c0];
    float4 wb = *(const float4*)&Wsh[k * 128 + c0 + 4];
    float xs[4] = {xv.x, xv.y, xv.z, xv.w};
    float wv[8] = {wa.x, wa.y, wa.z, wa.w, wb.x, wb.y, wb.z, wb.w};
#pragma unroll
    for (int i = 0; i < 4; ++i)
#pragma unroll
      for (int j = 0; j < 8; ++j) acc[i][j] += xs[i] * wv[j];
  }
  int head = cg >> 2;
  float ps[4], pd[4];
#pragma unroll
  for (int i = 0; i < 4; ++i) {
    float s = 0.0f, d = 0.0f;
#pragma unroll
    for (int j = 0; j < 8; ++j) {
      s += acc[i][j] * asrc[c0 + j];
      d += acc[i][j] * adst[c0 + j];
    }
    ps[i] = s; pd[i] = d;
  }
#pragma unroll
  for (int off = 1; off < 4; off <<= 1) {
#pragma unroll
    for (int i = 0; i < 4; ++i) {
      ps[i] += __shfl_xor(ps[i], off);
      pd[i] += __shfl_xor(pd[i], off);
    }
  }
#pragma unroll
  for (int i = 0; i < 4; ++i) {
    int node = node0 + n0 + i;
    if (node < NT) {
      float4 o0 = make_float4(acc[i][0], acc[i][1], acc[i][2], acc[i][3]);
      float4 o1 = make_float4(acc[i][4], acc[i][5], acc[i][6], acc[i][7]);
      *(float4*)&h[node * 128 + c0] = o0;
      *(float4*)&h[node * 128 + c0 + 4] = o1;
      if ((cg & 3) == 0) {
        es[node * 4 + head] = ps[i];
        ed[node * 4 + head] = pd[i];
      }
    }
  }
}

// ---------------- agg1: per-node softmax + aggregate, heads=4, ch=32 ----------------
// Phase 1: edge-parallel (m, den) with shfl merge. Phase 2: per-edge weight
// computed ONCE, shared via LDS; 128 channel threads do coalesced FMA.
__global__ __launch_bounds__(128) void k_agg1(const int* __restrict__ rp, const int* __restrict__ adj,
                                              const float* __restrict__ es, const float* __restrict__ ed,
                                              const float* __restrict__ h, const float* __restrict__ b1,
                                              float* __restrict__ out) {
  __shared__ float sm_m[4], sm_inv[4], sm_ws[4];
  __shared__ float red_m[8], red_d[8];
  __shared__ int sbuf[32];
  __shared__ float wbuf[32 * 4];
  int n = blockIdx.x;
  int t = threadIdx.x;
  int h4 = t & 3;  // head for weight work
  int rs = rp[n], re = rp[n + 1];
  float edst = ed[n * 4 + h4];
  float vs = lrelu(es[n * 4 + h4] + edst);  // self-loop logit
  float m = -1e30f, den = 0.0f;
  for (int j = rs + (t >> 2); j < re; j += 32) {
    int s = adj[j];
    float v = lrelu(es[s * 4 + h4] + edst);
    if (v > m) { den = den * expf(m - v) + 1.0f; m = v; }
    else den += expf(v - m);
  }
  // merge (m,den) across the 16 same-head lanes within the wave
#pragma unroll
  for (int off = 4; off <= 32; off <<= 1) {
    float m2 = __shfl_xor(m, off);
    float d2 = __shfl_xor(den, off);
    float mm = fmaxf(m, m2);
    den = den * expf(m - mm) + d2 * expf(m2 - mm);
    m = mm;
  }
  int wv = t >> 6;
  if ((t & 63) < 4) { red_m[wv * 4 + h4] = m; red_d[wv * 4 + h4] = den; }
  __syncthreads();
  if (t < 4) {
    float m0 = red_m[h4], d0 = red_d[h4];
    float m1 = red_m[4 + h4], d1 = red_d[4 + h4];
    float mm = fmaxf(m0, m1);
    float dd = d0 * expf(m0 - mm) + d1 * expf(m1 - mm);
    float mf = fmaxf(mm, vs);  // include self-loop
    dd = dd * expf(mm - mf) + expf(vs - mf);
    float inv = 1.0f / dd;
    sm_m[h4] = mf;
    sm_inv[h4] = inv;
    sm_ws[h4] = expf(vs - mf) * inv;
  }
  __syncthreads();
  int hc = t >> 5;  // head for this channel
  float m_h = sm_m[h4], inv_h = sm_inv[h4];
  float acc = sm_ws[hc] * h[n * 128 + t];
  for (int base = rs; base < re; base += 32) {
    int j = base + (t >> 2);
    if (j < re) {
      int s = adj[j];
      if (h4 == 0) sbuf[t >> 2] = s;
      float v = lrelu(es[s * 4 + h4] + edst);
      wbuf[(t >> 2) * 4 + h4] = expf(v - m_h) * inv_h;
    }
    __syncthreads();
    int cnt = min(32, re - base);
    for (int e = 0; e < cnt; ++e) {
      acc += wbuf[e * 4 + hc] * h[sbuf[e] * 128 + t];
    }
    __syncthreads();
  }
  float o = acc + b1[t];
  out[n * 128 + t] = o > 0.0f ? o : expm1f(o);
}

// ---------------- GEMM2: h2 = h1out @ W2 (N x 128 -> N x 32), fused e_src/e_dst ----------------
__global__ __launch_bounds__(256) void k_gemm2(const float* __restrict__ hin, const float* __restrict__ W,
                                               const float* __restrict__ asrc, const float* __restrict__ adst,
                                               float* __restrict__ h2, float* __restrict__ es,
                                               float* __restrict__ ed) {
  __shared__ float Wsh[128 * 32];
  __shared__ float hT[128 * 72];
  int tid = threadIdx.x;
  int node0 = blockIdx.x * 64;
  for (int i = tid; i < 4096; i += 256) Wsh[i] = W[i];
  for (int i = tid; i < 8192; i += 256) {
    int ln = i >> 7, k = i & 127;
    int node = node0 + ln;
    hT[k * 72 + ln] = (node < NT) ? hin[node * 128 + k] : 0.0f;
  }
  __syncthreads();
  int cg = tid & 15, ng = tid >> 4;
  int c0 = cg * 2, n0 = ng * 4;
  float acc[4][2] = {{0.0f, 0.0f}, {0.0f, 0.0f}, {0.0f, 0.0f}, {0.0f, 0.0f}};
#pragma unroll 8
  for (int k = 0; k < 128; ++k) {
    float4 xv = *(const float4*)&hT[k * 72 + n0];
    float2 wv = *(const float2*)&Wsh[k * 32 + c0];
    acc[0][0] += xv.x * wv.x; acc[0][1] += xv.x * wv.y;
    acc[1][0] += xv.y * wv.x; acc[1][1] += xv.y * wv.y;
    acc[2][0] += xv.z * wv.x; acc[2][1] += xv.z * wv.y;
    acc[3][0] += xv.w * wv.x; acc[3][1] += xv.w * wv.y;
  }
  float ps[4], pd[4];
#pragma unroll
  for (int i = 0; i < 4; ++i) {
    ps[i] = acc[i][0] * asrc[c0] + acc[i][1] * asrc[c0 + 1];
    pd[i] = acc[i][0] * adst[c0] + acc[i][1] * adst[c0 + 1];
  }
#pragma unroll
  for (int off = 1; off < 16; off <<= 1) {
#pragma unroll
    for (int i = 0; i < 4; ++i) {
      ps[i] += __shfl_xor(ps[i], off);
      pd[i] += __shfl_xor(pd[i], off);
    }
  }
#pragma unroll
  for (int i = 0; i < 4; ++i) {
    int node = node0 + n0 + i;
    if (node < NT) {
      *(float2*)&h2[node * 32 + c0] = make_float2(acc[i][0], acc[i][1]);
      if (cg == 0) { es[node] = ps[i]; ed[node] = pd[i]; }
    }
  }
}

// ---------------- agg2: 1 wave per node, weights computed once ----------------
__global__ __launch_bounds__(64) void k_agg2(const int* __restrict__ rp, const int* __restrict__ adj,
                                             const float* __restrict__ es, const float* __restrict__ ed,
                                             const float* __restrict__ h, const float* __restrict__ b2,
                                             float* __restrict__ out) {
  __shared__ int sbuf[64];
  __shared__ float wbuf[64];
  int n = blockIdx.x;
  int l = threadIdx.x;
  int rs = rp[n], re = rp[n + 1];
  float edst = ed[n];
  float vs = lrelu(es[n] + edst);
  float m = -1e30f, den = 0.0f;
  for (int j = rs + l; j < re; j += 64) {
    float v = lrelu(es[adj[j]] + edst);
    if (v > m) { den = den * expf(m - v) + 1.0f; m = v; }
    else den += expf(v - m);
  }
#pragma unroll
  for (int off = 1; off <= 32; off <<= 1) {
    float m2 = __shfl_xor(m, off);
    float d2 = __shfl_xor(den, off);
    float mm = fmaxf(m, m2);
    den = den * expf(m - mm) + d2 * expf(m2 - mm);
    m = mm;
  }
  float mf = fmaxf(m, vs);
  float dd = den * expf(m - mf) + expf(vs - mf);
  float inv = 1.0f / dd;
  int c = l & 31, half = l >> 5;
  float acc = (half == 0) ? expf(vs - mf) * inv * h[n * 32 + c] : 0.0f;
  for (int base = rs; base < re; base += 64) {
    int j = base + l;
    if (j < re) {
      int s = adj[j];
      sbuf[l] = s;
      wbuf[l] = expf(lrelu(es[s] + edst) - mf) * inv;
    }
    __syncthreads();
    int cnt = min(64, re - base);
    for (int e = half; e < cnt; e += 2) {
      acc += wbuf[e] * h[sbuf[e] * 32 + c];
    }
    __syncthreads();
  }
  acc += __shfl_xor(acc, 32);
  if (half == 0) {
    float o = acc + b2[c];
    out[n * 32 + c] = o > 0.0f ? o : expm1f(o);
  }
}

// ---------------- pooling + classifier: one block per graph, zero atomics ----------------
__global__ __launch_bounds__(256) void k_pool2(const float* __restrict__ h, const int* __restrict__ batch,
                                               const float* __restrict__ Wc, const float* __restrict__ bc,
                                               float* __restrict__ out) {
  int g = blockIdx.x;
  int lo = 0, hi = NT;
  while (lo < hi) { int mid = (lo + hi) >> 1; if (batch[mid] < g) lo = mid + 1; else hi = mid; }
  int start = lo;
  hi = NT;
  while (lo < hi) { int mid = (lo + hi) >> 1; if (batch[mid] < g + 1) lo = mid + 1; else hi = mid; }
  int end = lo;

  int t = threadIdx.x, c = t & 31, r = t >> 5;
  float acc = 0.0f;
  for (int n = start + r; n < end; n += 8) acc += h[n * 32 + c];
  __shared__ float sh[256];
  sh[t] = acc;
  __syncthreads();
  if (r == 0) {
    float s = 0.0f;
#pragma unroll
    for (int i = 0; i < 8; ++i) s += sh[i * 32 + c];
    float cnt = (float)(end - start);
    float inv = 1.0f / fmaxf(cnt, 1.0f);
    float v = s * inv * Wc[c];
#pragma unroll
    for (int off = 16; off >= 1; off >>= 1) v += __shfl_xor(v, off);
    if (c == 0) out[g] = v + bc[0];
  }
}

extern "C" void kernel_launch(void* const* d_in, const int* in_sizes, int n_in,
                              void* d_out, int out_size, void* d_ws, size_t ws_size,
                              hipStream_t stream) {
  const float* x = (const float*)d_in[0];
  const int* ei = (const int*)d_in[1];
  const int* src = ei;
  const int* dst = ei + ET;
  const int* batch = (const int*)d_in[2];
  const float* W1 = (const float*)d_in[3];
  const float* asrc1 = (const float*)d_in[4];
  const float* adst1 = (const float*)d_in[5];
  const float* b1 = (const float*)d_in[6];
  const float* W2 = (const float*)d_in[7];
  const float* asrc2 = (const float*)d_in[8];
  const float* adst2 = (const float*)d_in[9];
  const float* b2 = (const float*)d_in[10];
  const float* Wc = (const float*)d_in[11];
  const float* bc = (const float*)d_in[12];
  float* out = (float*)d_out;
  char* ws = (char*)d_ws;

  int* row_ptr = (int*)(ws + 0);
  int* cursor = (int*)(ws + 400128);
  int* partials = (int*)(ws + 800256);
  int* adj = (int*)(ws + 800768);
  float* es1 = (float*)(ws + 7200768);
  float* ed1 = (float*)(ws + 8800768);
  float* es2 = (float*)(ws + 10400768);
  float* ed2 = (float*)(ws + 10800768);
  float* h1 = (float*)(ws + 11217664);
  float* h1o = (float*)(ws + 62417664);
  float* h2 = h1;                        // h1 dead after agg1
  float* h2o = (float*)(ws + 24017664);  // inside dead h1 region

  // zero edge counts
  hipMemsetAsync(cursor, 0, NT * 4, stream);

  // CSR build (shared by both layers)
  k_count<<<(ET + 255) / 256, 256, 0, stream>>>(dst, cursor);
  k_scan1<<<98, 256, 0, stream>>>(cursor, row_ptr, partials);
  k_scan2<<<1, 64, 0, stream>>>(partials);
  k_scan3<<<(NT + 255) / 256, 256, 0, stream>>>(row_ptr, cursor, partials);
  k_scatter<<<(ET + 255) / 256, 256, 0, stream>>>(src, dst, cursor, adj);

  // layer 1
  k_gemm1<<<(NT + 63) / 64, 256, 0, stream>>>(x, W1, asrc1, adst1, h1, es1, ed1);
  k_agg1<<<NT, 128, 0, stream>>>(row_ptr, adj, es1, ed1, h1, b1, h1o);

  // layer 2
  k_gemm2<<<(NT + 63) / 64, 256, 0, stream>>>(h1o, W2, asrc2, adst2, h2, es2, ed2);
  k_agg2<<<NT, 64, 0, stream>>>(row_ptr, adj, es2, ed2, h2, b2, h2o);

  // pool + classify (no atomics: batch is sorted, binary-search graph ranges)
  k_pool2<<<GT, 256, 0, stream>>>(h2o, batch, Wc, bc, out);
}

// Round 4
// 535.744 us; speedup vs baseline: 2.5813x; 1.0426x over previous
//
#include <hip/hip_runtime.h>
#include <math.h>

#define NT 100000
#define ET 1600000
#define GT 128

__device__ __forceinline__ float lrelu(float v) { return v > 0.0f ? v : 0.2f * v; }

// ---------------- CSR build ----------------
__global__ void k_count(const int* __restrict__ dst, int* __restrict__ counts) {
  int e = blockIdx.x * 256 + threadIdx.x;
  if (e < ET) atomicAdd(&counts[dst[e]], 1);
}

__global__ __launch_bounds__(256) void k_scan1(const int* __restrict__ counts,
                                               int* __restrict__ scanned,
                                               int* __restrict__ partials) {
  __shared__ int sh[256];
  int t = threadIdx.x;
  int base = blockIdx.x * 1024 + t * 4;
  int v[4];
#pragma unroll
  for (int i = 0; i < 4; ++i) v[i] = (base + i < NT) ? counts[base + i] : 0;
  int tsum = v[0] + v[1] + v[2] + v[3];
  sh[t] = tsum;
  __syncthreads();
  for (int off = 1; off < 256; off <<= 1) {
    int xv = (t >= off) ? sh[t - off] : 0;
    __syncthreads();
    sh[t] += xv;
    __syncthreads();
  }
  int ex = sh[t] - tsum;
#pragma unroll
  for (int i = 0; i < 4; ++i) {
    if (base + i < NT) scanned[base + i] = ex;
    ex += v[i];
  }
  if (t == 255) partials[blockIdx.x] = sh[255];
}

__global__ void k_scan2(int* partials) {
  if (threadIdx.x == 0) {
    int s = 0;
    for (int i = 0; i < 98; ++i) { int v = partials[i]; partials[i] = s; s += v; }
    partials[98] = s;
  }
}

__global__ void k_scan3(int* __restrict__ rp, int* __restrict__ cursor,
                        const int* __restrict__ partials) {
  int i = blockIdx.x * 256 + threadIdx.x;
  if (i < NT) {
    int v = rp[i] + partials[i >> 10];
    rp[i] = v;
    cursor[i] = v;
    if (i == 0) rp[NT] = ET;
  }
}

__global__ void k_scatter(const int* __restrict__ src, const int* __restrict__ dst,
                          int* __restrict__ cursor, int* __restrict__ adj) {
  int e = blockIdx.x * 256 + threadIdx.x;
  if (e < ET) {
    int pos = atomicAdd(&cursor[dst[e]], 1);
    adj[pos] = src[e];
  }
}

// ---------------- GEMM1: h1 = x @ W1 (N x 32 -> N x 128), fused e_src/e_dst ----------------
__global__ __launch_bounds__(256) void k_gemm1(const float* __restrict__ x, const float* __restrict__ W,
                                               const float* __restrict__ asrc, const float* __restrict__ adst,
                                               float* __restrict__ h, float* __restrict__ es,
                                               float* __restrict__ ed) {
  __shared__ float Wsh[32 * 128];
  __shared__ float xT[32 * 72];
  int tid = threadIdx.x;
  int node0 = blockIdx.x * 64;
  for (int i = tid; i < 4096; i += 256) Wsh[i] = W[i];
  for (int i = tid; i < 2048; i += 256) {
    int ln = i >> 5, k = i & 31;
    int node = node0 + ln;
    xT[k * 72 + ln] = (node < NT) ? x[node * 32 + k] : 0.0f;
  }
  __syncthreads();
  int cg = tid & 15, ng = tid >> 4;
  int c0 = cg * 8, n0 = ng * 4;
  float acc[4][8];
#pragma unroll
  for (int i = 0; i < 4; ++i)
#pragma unroll
    for (int j = 0; j < 8; ++j) acc[i][j] = 0.0f;
#pragma unroll
  for (int k = 0; k < 32; ++k) {
    float4 xv = *(const float4*)&xT[k * 72 + n0];
    float4 wa = *(const float4*)&Wsh[k * 128 + c0];
    float4 wb = *(const float4*)&Wsh[k * 128 + c0 + 4];
    float xs[4] = {xv.x, xv.y, xv.z, xv.w};
    float wv[8] = {wa.x, wa.y, wa.z, wa.w, wb.x, wb.y, wb.z, wb.w};
#pragma unroll
    for (int i = 0; i < 4; ++i)
#pragma unroll
      for (int j = 0; j < 8; ++j) acc[i][j] += xs[i] * wv[j];
  }
  int head = cg >> 2;
  float ps[4], pd[4];
#pragma unroll
  for (int i = 0; i < 4; ++i) {
    float s = 0.0f, d = 0.0f;
#pragma unroll
    for (int j = 0; j < 8; ++j) {
      s += acc[i][j] * asrc[c0 + j];
      d += acc[i][j] * adst[c0 + j];
    }
    ps[i] = s; pd[i] = d;
  }
#pragma unroll
  for (int off = 1; off < 4; off <<= 1) {
#pragma unroll
    for (int i = 0; i < 4; ++i) {
      ps[i] += __shfl_xor(ps[i], off);
      pd[i] += __shfl_xor(pd[i], off);
    }
  }
#pragma unroll
  for (int i = 0; i < 4; ++i) {
    int node = node0 + n0 + i;
    if (node < NT) {
      float4 o0 = make_float4(acc[i][0], acc[i][1], acc[i][2], acc[i][3]);
      float4 o1 = make_float4(acc[i][4], acc[i][5], acc[i][6], acc[i][7]);
      *(float4*)&h[node * 128 + c0] = o0;
      *(float4*)&h[node * 128 + c0 + 4] = o1;
      if ((cg & 3) == 0) {
        es[node * 4 + head] = ps[i];
        ed[node * 4 + head] = pd[i];
      }
    }
  }
}

// ---------------- agg1: per-node softmax + aggregate, heads=4, ch=32 ----------------
// Fast path (deg<=32): logits computed ONCE into registers, plain fmax shuffle
// tree, one __expf per (edge,head); weights to LDS; 3 barriers total.
__global__ __launch_bounds__(128) void k_agg1(const int* __restrict__ rp, const int* __restrict__ adj,
                                              const float* __restrict__ es, const float* __restrict__ ed,
                                              const float* __restrict__ h, const float* __restrict__ b1,
                                              float* __restrict__ out) {
  __shared__ float sm_m[4], sm_inv[4], sm_ws[4];
  __shared__ float red_m[8], red_d[8];
  __shared__ int sbuf[32];
  __shared__ float wbuf[32 * 4];
  int n = blockIdx.x;
  int t = threadIdx.x;
  int h4 = t & 3;
  int slot = t >> 2;
  int wv = t >> 6;
  int rs = rp[n], re = rp[n + 1];
  int deg = re - rs;
  float edst = ed[n * 4 + h4];
  float vs = lrelu(es[n * 4 + h4] + edst);  // self-loop logit
  int hc = t >> 5;

  if (deg <= 32) {
    float v = -1e30f;
    if (slot < deg) {
      int s = adj[rs + slot];
      if (h4 == 0) sbuf[slot] = s;
      v = lrelu(es[s * 4 + h4] + edst);
    }
    float m = v;
#pragma unroll
    for (int off = 4; off <= 32; off <<= 1) m = fmaxf(m, __shfl_xor(m, off));
    if ((t & 63) < 4) red_m[wv * 4 + h4] = m;
    __syncthreads();
    m = fmaxf(fmaxf(red_m[h4], red_m[4 + h4]), vs);
    float ex = (slot < deg) ? __expf(v - m) : 0.0f;
    float d = ex;
#pragma unroll
    for (int off = 4; off <= 32; off <<= 1) d += __shfl_xor(d, off);
    __syncthreads();
    if ((t & 63) < 4) red_d[wv * 4 + h4] = d;
    __syncthreads();
    float den = red_d[h4] + red_d[4 + h4] + __expf(vs - m);
    float inv = 1.0f / den;
    wbuf[t] = ex * inv;                       // t == slot*4 + h4
    if (t < 4) sm_ws[t] = __expf(vs - m) * inv;
    __syncthreads();
    float acc = sm_ws[hc] * h[n * 128 + t];
    for (int e = 0; e < deg; ++e) {
      acc += wbuf[e * 4 + hc] * h[sbuf[e] * 128 + t];
    }
    float o = acc + b1[t];
    out[n * 128 + t] = o > 0.0f ? o : __expf(o) - 1.0f;
    return;
  }

  // generic path (rare): chunked two-pass with online merge
  float m = -1e30f, den = 0.0f;
  for (int j = rs + slot; j < re; j += 32) {
    int s = adj[j];
    float v = lrelu(es[s * 4 + h4] + edst);
    if (v > m) { den = den * __expf(m - v) + 1.0f; m = v; }
    else den += __expf(v - m);
  }
#pragma unroll
  for (int off = 4; off <= 32; off <<= 1) {
    float m2 = __shfl_xor(m, off);
    float d2 = __shfl_xor(den, off);
    float mm = fmaxf(m, m2);
    den = den * __expf(m - mm) + d2 * __expf(m2 - mm);
    m = mm;
  }
  if ((t & 63) < 4) { red_m[wv * 4 + h4] = m; red_d[wv * 4 + h4] = den; }
  __syncthreads();
  if (t < 4) {
    float m0 = red_m[h4], d0 = red_d[h4];
    float m1 = red_m[4 + h4], d1 = red_d[4 + h4];
    float mm = fmaxf(m0, m1);
    float dd = d0 * __expf(m0 - mm) + d1 * __expf(m1 - mm);
    float mf = fmaxf(mm, vs);
    dd = dd * __expf(mm - mf) + __expf(vs - mf);
    float inv = 1.0f / dd;
    sm_m[h4] = mf;
    sm_inv[h4] = inv;
    sm_ws[h4] = __expf(vs - mf) * inv;
  }
  __syncthreads();
  float m_h = sm_m[h4], inv_h = sm_inv[h4];
  float acc = sm_ws[hc] * h[n * 128 + t];
  for (int base = rs; base < re; base += 32) {
    int j = base + slot;
    if (j < re) {
      int s = adj[j];
      if (h4 == 0) sbuf[slot] = s;
      float v = lrelu(es[s * 4 + h4] + edst);
      wbuf[slot * 4 + h4] = __expf(v - m_h) * inv_h;
    }
    __syncthreads();
    int cnt = min(32, re - base);
    for (int e = 0; e < cnt; ++e) {
      acc += wbuf[e * 4 + hc] * h[sbuf[e] * 128 + t];
    }
    __syncthreads();
  }
  float o = acc + b1[t];
  out[n * 128 + t] = o > 0.0f ? o : __expf(o) - 1.0f;
}

// ---------------- GEMM2: h2 = h1out @ W2 (N x 128 -> N x 32), fused e_src/e_dst ----------------
__global__ __launch_bounds__(256) void k_gemm2(const float* __restrict__ hin, const float* __restrict__ W,
                                               const float* __restrict__ asrc, const float* __restrict__ adst,
                                               float* __restrict__ h2, float* __restrict__ es,
                                               float* __restrict__ ed) {
  __shared__ float Wsh[128 * 32];
  __shared__ float hT[128 * 72];
  int tid = threadIdx.x;
  int node0 = blockIdx.x * 64;
  for (int i = tid; i < 4096; i += 256) Wsh[i] = W[i];
  for (int i = tid; i < 8192; i += 256) {
    int ln = i >> 7, k = i & 127;
    int node = node0 + ln;
    hT[k * 72 + ln] = (node < NT) ? hin[node * 128 + k] : 0.0f;
  }
  __syncthreads();
  int cg = tid & 15, ng = tid >> 4;
  int c0 = cg * 2, n0 = ng * 4;
  float acc[4][2] = {{0.0f, 0.0f}, {0.0f, 0.0f}, {0.0f, 0.0f}, {0.0f, 0.0f}};
#pragma unroll 8
  for (int k = 0; k < 128; ++k) {
    float4 xv = *(const float4*)&hT[k * 72 + n0];
    float2 wv = *(const float2*)&Wsh[k * 32 + c0];
    acc[0][0] += xv.x * wv.x; acc[0][1] += xv.x * wv.y;
    acc[1][0] += xv.y * wv.x; acc[1][1] += xv.y * wv.y;
    acc[2][0] += xv.z * wv.x; acc[2][1] += xv.z * wv.y;
    acc[3][0] += xv.w * wv.x; acc[3][1] += xv.w * wv.y;
  }
  float ps[4], pd[4];
#pragma unroll
  for (int i = 0; i < 4; ++i) {
    ps[i] = acc[i][0] * asrc[c0] + acc[i][1] * asrc[c0 + 1];
    pd[i] = acc[i][0] * adst[c0] + acc[i][1] * adst[c0 + 1];
  }
#pragma unroll
  for (int off = 1; off < 16; off <<= 1) {
#pragma unroll
    for (int i = 0; i < 4; ++i) {
      ps[i] += __shfl_xor(ps[i], off);
      pd[i] += __shfl_xor(pd[i], off);
    }
  }
#pragma unroll
  for (int i = 0; i < 4; ++i) {
    int node = node0 + n0 + i;
    if (node < NT) {
      *(float2*)&h2[node * 32 + c0] = make_float2(acc[i][0], acc[i][1]);
      if (cg == 0) { es[node] = ps[i]; ed[node] = pd[i]; }
    }
  }
}

// ---------------- agg2: 1 wave per node, 4 nodes/block, wave-local (no barriers) ----------------
__global__ __launch_bounds__(256) void k_agg2(const int* __restrict__ rp, const int* __restrict__ adj,
                                              const float* __restrict__ es, const float* __restrict__ ed,
                                              const float* __restrict__ h, const float* __restrict__ b2,
                                              float* __restrict__ out) {
  __shared__ int sbuf_all[4][64];
  __shared__ float wbuf_all[4][64];
  int wv = threadIdx.x >> 6;
  int l = threadIdx.x & 63;
  int n = blockIdx.x * 4 + wv;
  if (n >= NT) return;
  int* sbuf = sbuf_all[wv];
  float* wbuf = wbuf_all[wv];
  int rs = rp[n], re = rp[n + 1];
  int deg = re - rs;
  float edst = ed[n];
  float vs = lrelu(es[n] + edst);
  int c = l & 31, half = l >> 5;

  if (deg <= 64) {
    float v = -1e30f;
    if (l < deg) {
      int s = adj[rs + l];
      sbuf[l] = s;
      v = lrelu(es[s] + edst);
    }
    float m = v;
#pragma unroll
    for (int off = 1; off <= 32; off <<= 1) m = fmaxf(m, __shfl_xor(m, off));
    m = fmaxf(m, vs);
    float ex = (l < deg) ? __expf(v - m) : 0.0f;
    float d = ex;
#pragma unroll
    for (int off = 1; off <= 32; off <<= 1) d += __shfl_xor(d, off);
    float inv = 1.0f / (d + __expf(vs - m));
    if (l < deg) wbuf[l] = ex * inv;
    __builtin_amdgcn_wave_barrier();
    float acc = (half == 0) ? __expf(vs - m) * inv * h[n * 32 + c] : 0.0f;
    for (int e = half; e < deg; e += 2) {
      acc += wbuf[e] * h[sbuf[e] * 32 + c];
    }
    acc += __shfl_xor(acc, 32);
    if (half == 0) {
      float o = acc + b2[c];
      out[n * 32 + c] = o > 0.0f ? o : __expf(o) - 1.0f;
    }
    return;
  }

  // generic path (rare)
  float m = -1e30f, den = 0.0f;
  for (int j = rs + l; j < re; j += 64) {
    float v = lrelu(es[adj[j]] + edst);
    if (v > m) { den = den * __expf(m - v) + 1.0f; m = v; }
    else den += __expf(v - m);
  }
#pragma unroll
  for (int off = 1; off <= 32; off <<= 1) {
    float m2 = __shfl_xor(m, off);
    float d2 = __shfl_xor(den, off);
    float mm = fmaxf(m, m2);
    den = den * __expf(m - mm) + d2 * __expf(m2 - mm);
    m = mm;
  }
  float mf = fmaxf(m, vs);
  float dd = den * __expf(m - mf) + __expf(vs - mf);
  float inv = 1.0f / dd;
  float acc = (half == 0) ? __expf(vs - mf) * inv * h[n * 32 + c] : 0.0f;
  for (int base = rs; base < re; base += 64) {
    int j = base + l;
    if (j < re) {
      int s = adj[j];
      sbuf[l] = s;
      wbuf[l] = __expf(lrelu(es[s] + edst) - mf) * inv;
    }
    __builtin_amdgcn_wave_barrier();
    int cnt = min(64, re - base);
    for (int e = half; e < cnt; e += 2) {
      acc += wbuf[e] * h[sbuf[e] * 32 + c];
    }
    __builtin_amdgcn_wave_barrier();
  }
  acc += __shfl_xor(acc, 32);
  if (half == 0) {
    float o = acc + b2[c];
    out[n * 32 + c] = o > 0.0f ? o : __expf(o) - 1.0f;
  }
}

// ---------------- pooling + classifier: one block per graph, zero atomics ----------------
__global__ __launch_bounds__(256) void k_pool2(const float* __restrict__ h, const int* __restrict__ batch,
                                               const float* __restrict__ Wc, const float* __restrict__ bc,
                                               float* __restrict__ out) {
  int g = blockIdx.x;
  int lo = 0, hi = NT;
  while (lo < hi) { int mid = (lo + hi) >> 1; if (batch[mid] < g) lo = mid + 1; else hi = mid; }
  int start = lo;
  hi = NT;
  while (lo < hi) { int mid = (lo + hi) >> 1; if (batch[mid] < g + 1) lo = mid + 1; else hi = mid; }
  int end = lo;

  int t = threadIdx.x, c = t & 31, r = t >> 5;
  float acc = 0.0f;
  for (int n = start + r; n < end; n += 8) acc += h[n * 32 + c];
  __shared__ float sh[256];
  sh[t] = acc;
  __syncthreads();
  if (r == 0) {
    float s = 0.0f;
#pragma unroll
    for (int i = 0; i < 8; ++i) s += sh[i * 32 + c];
    float cnt = (float)(end - start);
    float inv = 1.0f / fmaxf(cnt, 1.0f);
    float v = s * inv * Wc[c];
#pragma unroll
    for (int off = 16; off >= 1; off >>= 1) v += __shfl_xor(v, off);
    if (c == 0) out[g] = v + bc[0];
  }
}

extern "C" void kernel_launch(void* const* d_in, const int* in_sizes, int n_in,
                              void* d_out, int out_size, void* d_ws, size_t ws_size,
                              hipStream_t stream) {
  const float* x = (const float*)d_in[0];
  const int* ei = (const int*)d_in[1];
  const int* src = ei;
  const int* dst = ei + ET;
  const int* batch = (const int*)d_in[2];
  const float* W1 = (const float*)d_in[3];
  const float* asrc1 = (const float*)d_in[4];
  const float* adst1 = (const float*)d_in[5];
  const float* b1 = (const float*)d_in[6];
  const float* W2 = (const float*)d_in[7];
  const float* asrc2 = (const float*)d_in[8];
  const float* adst2 = (const float*)d_in[9];
  const float* b2 = (const float*)d_in[10];
  const float* Wc = (const float*)d_in[11];
  const float* bc = (const float*)d_in[12];
  float* out = (float*)d_out;
  char* ws = (char*)d_ws;

  int* row_ptr = (int*)(ws + 0);
  int* cursor = (int*)(ws + 400128);
  int* partials = (int*)(ws + 800256);
  int* adj = (int*)(ws + 800768);
  float* es1 = (float*)(ws + 7200768);
  float* ed1 = (float*)(ws + 8800768);
  float* es2 = (float*)(ws + 10400768);
  float* ed2 = (float*)(ws + 10800768);
  float* h1 = (float*)(ws + 11217664);
  float* h1o = (float*)(ws + 62417664);
  float* h2 = h1;                        // h1 dead after agg1
  float* h2o = (float*)(ws + 24017664);  // inside dead h1 region

  hipMemsetAsync(cursor, 0, NT * 4, stream);

  // CSR build (shared by both layers)
  k_count<<<(ET + 255) / 256, 256, 0, stream>>>(dst, cursor);
  k_scan1<<<98, 256, 0, stream>>>(cursor, row_ptr, partials);
  k_scan2<<<1, 64, 0, stream>>>(partials);
  k_scan3<<<(NT + 255) / 256, 256, 0, stream>>>(row_ptr, cursor, partials);
  k_scatter<<<(ET + 255) / 256, 256, 0, stream>>>(src, dst, cursor, adj);

  // layer 1
  k_gemm1<<<(NT + 63) / 64, 256, 0, stream>>>(x, W1, asrc1, adst1, h1, es1, ed1);
  k_agg1<<<NT, 128, 0, stream>>>(row_ptr, adj, es1, ed1, h1, b1, h1o);

  // layer 2
  k_gemm2<<<(NT + 63) / 64, 256, 0, stream>>>(h1o, W2, asrc2, adst2, h2, es2, ed2);
  k_agg2<<<(NT + 3) / 4, 256, 0, stream>>>(row_ptr, adj, es2, ed2, h2, b2, h2o);

  // pool + classify
  k_pool2<<<GT, 256, 0, stream>>>(h2o, batch, Wc, bc, out);
}

// Round 5
// 500.633 us; speedup vs baseline: 2.7623x; 1.0701x over previous
//
#include <hip/hip_runtime.h>
#include <math.h>

#define NT 100000
#define ET 1600000
#define GT 128

__device__ __forceinline__ float lrelu(float v) { return v > 0.0f ? v : 0.2f * v; }

// ---------------- CSR build ----------------
__global__ void k_count(const int* __restrict__ dst, int* __restrict__ counts) {
  int e = blockIdx.x * 256 + threadIdx.x;
  if (e < ET) atomicAdd(&counts[dst[e]], 1);
}

__global__ __launch_bounds__(256) void k_scan1(const int* __restrict__ counts,
                                               int* __restrict__ scanned,
                                               int* __restrict__ partials) {
  __shared__ int sh[256];
  int t = threadIdx.x;
  int base = blockIdx.x * 1024 + t * 4;
  int v[4];
#pragma unroll
  for (int i = 0; i < 4; ++i) v[i] = (base + i < NT) ? counts[base + i] : 0;
  int tsum = v[0] + v[1] + v[2] + v[3];
  sh[t] = tsum;
  __syncthreads();
  for (int off = 1; off < 256; off <<= 1) {
    int xv = (t >= off) ? sh[t - off] : 0;
    __syncthreads();
    sh[t] += xv;
    __syncthreads();
  }
  int ex = sh[t] - tsum;
#pragma unroll
  for (int i = 0; i < 4; ++i) {
    if (base + i < NT) scanned[base + i] = ex;
    ex += v[i];
  }
  if (t == 255) partials[blockIdx.x] = sh[255];
}

__global__ void k_scan2(int* partials) {
  if (threadIdx.x == 0) {
    int s = 0;
    for (int i = 0; i < 98; ++i) { int v = partials[i]; partials[i] = s; s += v; }
    partials[98] = s;
  }
}

__global__ void k_scan3(int* __restrict__ rp, int* __restrict__ cursor,
                        const int* __restrict__ partials) {
  int i = blockIdx.x * 256 + threadIdx.x;
  if (i < NT) {
    int v = rp[i] + partials[i >> 10];
    rp[i] = v;
    cursor[i] = v;
    if (i == 0) rp[NT] = ET;
  }
}

__global__ void k_scatter(const int* __restrict__ src, const int* __restrict__ dst,
                          int* __restrict__ cursor, int* __restrict__ adj) {
  int e = blockIdx.x * 256 + threadIdx.x;
  if (e < ET) {
    int pos = atomicAdd(&cursor[dst[e]], 1);
    adj[pos] = src[e];
  }
}

// ---------------- prep: AB[k][j] = sum_c W1[k][h*32+c] * a[h][c]  (j<4: src, j>=4: dst) ----------------
__global__ void k_prep(const float* __restrict__ W1, const float* __restrict__ as1,
                       const float* __restrict__ ad1, float* __restrict__ AB) {
  int t = threadIdx.x;  // 256
  int k = t >> 3, j = t & 7;
  const float* a = (j < 4) ? as1 : ad1;
  int h = j & 3;
  float s = 0.0f;
  for (int c = 0; c < 32; ++c) s += W1[k * 128 + h * 32 + c] * a[h * 32 + c];
  AB[t] = s;  // AB[k*8 + j]
}

// ---------------- att1: es1/ed1 = x @ AB (N x 32 x 8) ----------------
__global__ __launch_bounds__(256) void k_att1(const float* __restrict__ x, const float* __restrict__ AB,
                                              float* __restrict__ es, float* __restrict__ ed) {
  __shared__ float xsh[32 * 33];
  __shared__ float absh[256];
  int t = threadIdx.x;
  int n0 = blockIdx.x * 32;
  absh[t] = AB[t];
  for (int i = t; i < 1024; i += 256) {
    int ln = i >> 5, k = i & 31;
    int node = n0 + ln;
    xsh[ln * 33 + k] = (node < NT) ? x[node * 32 + k] : 0.0f;
  }
  __syncthreads();
  int ln = t >> 3, j = t & 7;
  int node = n0 + ln;
  if (node < NT) {
    float s = 0.0f;
#pragma unroll
    for (int k = 0; k < 32; ++k) s += xsh[ln * 33 + k] * absh[k * 8 + j];
    if (j < 4) es[node * 4 + j] = s;
    else ed[node * 4 + (j - 4)] = s;
  }
}

// ---------------- agg1 in INPUT space: y_h = sum_s alpha_s^h x[s]; out = y_h @ W1_h + b1, ELU ----------------
__global__ __launch_bounds__(128) void k_agg1(const int* __restrict__ rp, const int* __restrict__ adj,
                                              const float* __restrict__ es, const float* __restrict__ ed,
                                              const float* __restrict__ x, const float* __restrict__ W1,
                                              const float* __restrict__ b1, float* __restrict__ out) {
  __shared__ float red_m[8], red_d[8];
  __shared__ float sm_m[4], sm_inv[4], sm_ws[4];
  __shared__ int sbuf[32];
  __shared__ float wbuf[128];
  __shared__ float ysh[4][33];
  int n = blockIdx.x;
  int t = threadIdx.x;
  int h4 = t & 3, slot = t >> 2, wv = t >> 6;
  int rs = rp[n], re = rp[n + 1];
  int deg = re - rs;
  float edst = ed[n * 4 + h4];
  float vs = lrelu(es[n * 4 + h4] + edst);  // self-loop logit
  int hc = t >> 5, c = t & 31;

  if (deg <= 32) {
    float v = -1e30f;
    if (slot < deg) {
      int s = adj[rs + slot];
      if (h4 == 0) sbuf[slot] = s;
      v = lrelu(es[s * 4 + h4] + edst);
    }
    float m = v;
#pragma unroll
    for (int off = 4; off <= 32; off <<= 1) m = fmaxf(m, __shfl_xor(m, off));
    if ((t & 63) < 4) red_m[wv * 4 + h4] = m;
    __syncthreads();
    m = fmaxf(fmaxf(red_m[h4], red_m[4 + h4]), vs);
    float ex = (slot < deg) ? __expf(v - m) : 0.0f;
    float d = ex;
#pragma unroll
    for (int off = 4; off <= 32; off <<= 1) d += __shfl_xor(d, off);
    if ((t & 63) < 4) red_d[wv * 4 + h4] = d;
    __syncthreads();
    float den = red_d[h4] + red_d[4 + h4] + __expf(vs - m);
    float inv = 1.0f / den;
    wbuf[t] = ex * inv;  // t == slot*4 + h4
    if (t < 4) sm_ws[t] = __expf(vs - m) * inv;
    __syncthreads();
    float acc = sm_ws[hc] * x[n * 32 + c];
    for (int e = 0; e < deg; ++e) {
      acc += wbuf[e * 4 + hc] * x[sbuf[e] * 32 + c];
    }
    ysh[hc][c] = acc;
    __syncthreads();
    float o = 0.0f;
#pragma unroll
    for (int k = 0; k < 32; ++k) o += ysh[hc][k] * W1[k * 128 + t];
    o += b1[t];
    out[n * 128 + t] = o > 0.0f ? o : __expf(o) - 1.0f;
    return;
  }

  // generic path (deg > 32, rare)
  float m = -1e30f, den = 0.0f;
  for (int j = rs + slot; j < re; j += 32) {
    int s = adj[j];
    float v = lrelu(es[s * 4 + h4] + edst);
    if (v > m) { den = den * __expf(m - v) + 1.0f; m = v; }
    else den += __expf(v - m);
  }
#pragma unroll
  for (int off = 4; off <= 32; off <<= 1) {
    float m2 = __shfl_xor(m, off);
    float d2 = __shfl_xor(den, off);
    float mm = fmaxf(m, m2);
    den = den * __expf(m - mm) + d2 * __expf(m2 - mm);
    m = mm;
  }
  if ((t & 63) < 4) { red_m[wv * 4 + h4] = m; red_d[wv * 4 + h4] = den; }
  __syncthreads();
  if (t < 4) {
    float m0 = red_m[h4], d0 = red_d[h4];
    float m1 = red_m[4 + h4], d1 = red_d[4 + h4];
    float mm = fmaxf(m0, m1);
    float dd = d0 * __expf(m0 - mm) + d1 * __expf(m1 - mm);
    float mf = fmaxf(mm, vs);
    dd = dd * __expf(mm - mf) + __expf(vs - mf);
    float inv = 1.0f / dd;
    sm_m[h4] = mf;
    sm_inv[h4] = inv;
    sm_ws[h4] = __expf(vs - mf) * inv;
  }
  __syncthreads();
  float m_h = sm_m[h4], inv_h = sm_inv[h4];
  float acc = sm_ws[hc] * x[n * 32 + c];
  for (int base = rs; base < re; base += 32) {
    int j = base + slot;
    if (j < re) {
      int s = adj[j];
      if (h4 == 0) sbuf[slot] = s;
      float v = lrelu(es[s * 4 + h4] + edst);
      wbuf[slot * 4 + h4] = __expf(v - m_h) * inv_h;
    }
    __syncthreads();
    int cnt = min(32, re - base);
    for (int e = 0; e < cnt; ++e) {
      acc += wbuf[e * 4 + hc] * x[sbuf[e] * 32 + c];
    }
    __syncthreads();
  }
  ysh[hc][c] = acc;
  __syncthreads();
  float o = 0.0f;
#pragma unroll
  for (int k = 0; k < 32; ++k) o += ysh[hc][k] * W1[k * 128 + t];
  o += b1[t];
  out[n * 128 + t] = o > 0.0f ? o : __expf(o) - 1.0f;
}

// ---------------- GEMM2: h2 = h1out @ W2 (N x 128 -> N x 32), fused e_src/e_dst ----------------
__global__ __launch_bounds__(256) void k_gemm2(const float* __restrict__ hin, const float* __restrict__ W,
                                               const float* __restrict__ asrc, const float* __restrict__ adst,
                                               float* __restrict__ h2, float* __restrict__ es,
                                               float* __restrict__ ed) {
  __shared__ float Wsh[128 * 32];
  __shared__ float hT[128 * 72];
  int tid = threadIdx.x;
  int node0 = blockIdx.x * 64;
  for (int i = tid; i < 4096; i += 256) Wsh[i] = W[i];
  for (int i = tid; i < 8192; i += 256) {
    int ln = i >> 7, k = i & 127;
    int node = node0 + ln;
    hT[k * 72 + ln] = (node < NT) ? hin[node * 128 + k] : 0.0f;
  }
  __syncthreads();
  int cg = tid & 15, ng = tid >> 4;
  int c0 = cg * 2, n0 = ng * 4;
  float acc[4][2] = {{0.0f, 0.0f}, {0.0f, 0.0f}, {0.0f, 0.0f}, {0.0f, 0.0f}};
#pragma unroll 8
  for (int k = 0; k < 128; ++k) {
    float4 xv = *(const float4*)&hT[k * 72 + n0];
    float2 wv = *(const float2*)&Wsh[k * 32 + c0];
    acc[0][0] += xv.x * wv.x; acc[0][1] += xv.x * wv.y;
    acc[1][0] += xv.y * wv.x; acc[1][1] += xv.y * wv.y;
    acc[2][0] += xv.z * wv.x; acc[2][1] += xv.z * wv.y;
    acc[3][0] += xv.w * wv.x; acc[3][1] += xv.w * wv.y;
  }
  float ps[4], pd[4];
#pragma unroll
  for (int i = 0; i < 4; ++i) {
    ps[i] = acc[i][0] * asrc[c0] + acc[i][1] * asrc[c0 + 1];
    pd[i] = acc[i][0] * adst[c0] + acc[i][1] * adst[c0 + 1];
  }
#pragma unroll
  for (int off = 1; off < 16; off <<= 1) {
#pragma unroll
    for (int i = 0; i < 4; ++i) {
      ps[i] += __shfl_xor(ps[i], off);
      pd[i] += __shfl_xor(pd[i], off);
    }
  }
#pragma unroll
  for (int i = 0; i < 4; ++i) {
    int node = node0 + n0 + i;
    if (node < NT) {
      *(float2*)&h2[node * 32 + c0] = make_float2(acc[i][0], acc[i][1]);
      if (cg == 0) { es[node] = ps[i]; ed[node] = pd[i]; }
    }
  }
}

// ---------------- agg2: 1 wave per node, 4 nodes/block, wave-local ----------------
__global__ __launch_bounds__(256) void k_agg2(const int* __restrict__ rp, const int* __restrict__ adj,
                                              const float* __restrict__ es, const float* __restrict__ ed,
                                              const float* __restrict__ h, const float* __restrict__ b2,
                                              float* __restrict__ out) {
  __shared__ int sbuf_all[4][64];
  __shared__ float wbuf_all[4][64];
  int wv = threadIdx.x >> 6;
  int l = threadIdx.x & 63;
  int n = blockIdx.x * 4 + wv;
  if (n >= NT) return;
  int* sbuf = sbuf_all[wv];
  float* wbuf = wbuf_all[wv];
  int rs = rp[n], re = rp[n + 1];
  int deg = re - rs;
  float edst = ed[n];
  float vs = lrelu(es[n] + edst);
  int c = l & 31, half = l >> 5;

  if (deg <= 64) {
    float v = -1e30f;
    if (l < deg) {
      int s = adj[rs + l];
      sbuf[l] = s;
      v = lrelu(es[s] + edst);
    }
    float m = v;
#pragma unroll
    for (int off = 1; off <= 32; off <<= 1) m = fmaxf(m, __shfl_xor(m, off));
    m = fmaxf(m, vs);
    float ex = (l < deg) ? __expf(v - m) : 0.0f;
    float d = ex;
#pragma unroll
    for (int off = 1; off <= 32; off <<= 1) d += __shfl_xor(d, off);
    float inv = 1.0f / (d + __expf(vs - m));
    if (l < deg) wbuf[l] = ex * inv;
    __builtin_amdgcn_wave_barrier();
    float acc = (half == 0) ? __expf(vs - m) * inv * h[n * 32 + c] : 0.0f;
    for (int e = half; e < deg; e += 2) {
      acc += wbuf[e] * h[sbuf[e] * 32 + c];
    }
    acc += __shfl_xor(acc, 32);
    if (half == 0) {
      float o = acc + b2[c];
      out[n * 32 + c] = o > 0.0f ? o : __expf(o) - 1.0f;
    }
    return;
  }

  // generic path (rare)
  float m = -1e30f, den = 0.0f;
  for (int j = rs + l; j < re; j += 64) {
    float v = lrelu(es[adj[j]] + edst);
    if (v > m) { den = den * __expf(m - v) + 1.0f; m = v; }
    else den += __expf(v - m);
  }
#pragma unroll
  for (int off = 1; off <= 32; off <<= 1) {
    float m2 = __shfl_xor(m, off);
    float d2 = __shfl_xor(den, off);
    float mm = fmaxf(m, m2);
    den = den * __expf(m - mm) + d2 * __expf(m2 - mm);
    m = mm;
  }
  float mf = fmaxf(m, vs);
  float dd = den * __expf(m - mf) + __expf(vs - mf);
  float inv = 1.0f / dd;
  float acc = (half == 0) ? __expf(vs - mf) * inv * h[n * 32 + c] : 0.0f;
  for (int base = rs; base < re; base += 64) {
    int j = base + l;
    if (j < re) {
      int s = adj[j];
      sbuf[l] = s;
      wbuf[l] = __expf(lrelu(es[s] + edst) - mf) * inv;
    }
    __builtin_amdgcn_wave_barrier();
    int cnt = min(64, re - base);
    for (int e = half; e < cnt; e += 2) {
      acc += wbuf[e] * h[sbuf[e] * 32 + c];
    }
    __builtin_amdgcn_wave_barrier();
  }
  acc += __shfl_xor(acc, 32);
  if (half == 0) {
    float o = acc + b2[c];
    out[n * 32 + c] = o > 0.0f ? o : __expf(o) - 1.0f;
  }
}

// ---------------- pooling + classifier: one block per graph, zero atomics ----------------
__global__ __launch_bounds__(256) void k_pool2(const float* __restrict__ h, const int* __restrict__ batch,
                                               const float* __restrict__ Wc, const float* __restrict__ bc,
                                               float* __restrict__ out) {
  int g = blockIdx.x;
  int lo = 0, hi = NT;
  while (lo < hi) { int mid = (lo + hi) >> 1; if (batch[mid] < g) lo = mid + 1; else hi = mid; }
  int start = lo;
  hi = NT;
  while (lo < hi) { int mid = (lo + hi) >> 1; if (batch[mid] < g + 1) lo = mid + 1; else hi = mid; }
  int end = lo;

  int t = threadIdx.x, c = t & 31, r = t >> 5;
  float acc = 0.0f;
  for (int n = start + r; n < end; n += 8) acc += h[n * 32 + c];
  __shared__ float sh[256];
  sh[t] = acc;
  __syncthreads();
  if (r == 0) {
    float s = 0.0f;
#pragma unroll
    for (int i = 0; i < 8; ++i) s += sh[i * 32 + c];
    float cnt = (float)(end - start);
    float inv = 1.0f / fmaxf(cnt, 1.0f);
    float v = s * inv * Wc[c];
#pragma unroll
    for (int off = 16; off >= 1; off >>= 1) v += __shfl_xor(v, off);
    if (c == 0) out[g] = v + bc[0];
  }
}

extern "C" void kernel_launch(void* const* d_in, const int* in_sizes, int n_in,
                              void* d_out, int out_size, void* d_ws, size_t ws_size,
                              hipStream_t stream) {
  const float* x = (const float*)d_in[0];
  const int* ei = (const int*)d_in[1];
  const int* src = ei;
  const int* dst = ei + ET;
  const int* batch = (const int*)d_in[2];
  const float* W1 = (const float*)d_in[3];
  const float* asrc1 = (const float*)d_in[4];
  const float* adst1 = (const float*)d_in[5];
  const float* b1 = (const float*)d_in[6];
  const float* W2 = (const float*)d_in[7];
  const float* asrc2 = (const float*)d_in[8];
  const float* adst2 = (const float*)d_in[9];
  const float* b2 = (const float*)d_in[10];
  const float* Wc = (const float*)d_in[11];
  const float* bc = (const float*)d_in[12];
  float* out = (float*)d_out;
  char* ws = (char*)d_ws;

  int* row_ptr = (int*)(ws + 0);          // 400128
  int* cursor = (int*)(ws + 400128);      // 400000
  int* partials = (int*)(ws + 800256);    // 512
  float* AB = (float*)(ws + 800768);      // 1024
  int* adj = (int*)(ws + 801792);         // 6.4MB -> 7201792
  float* es1 = (float*)(ws + 7201792);    // 1.6MB
  float* ed1 = (float*)(ws + 8801792);    // 1.6MB
  float* es2 = (float*)(ws + 10401792);   // 400KB
  float* ed2 = (float*)(ws + 10801792);   // 400KB
  float* h1o = (float*)(ws + 11201792);   // 51.2MB -> 62401792
  float* h2 = (float*)(ws + 62401792);    // 12.8MB -> 75201792
  float* h2o = (float*)(ws + 75201792);   // 12.8MB -> 88001792

  hipMemsetAsync(cursor, 0, NT * 4, stream);

  // CSR build (shared by both layers)
  k_count<<<(ET + 255) / 256, 256, 0, stream>>>(dst, cursor);
  k_scan1<<<98, 256, 0, stream>>>(cursor, row_ptr, partials);
  k_scan2<<<1, 64, 0, stream>>>(partials);
  k_scan3<<<(NT + 255) / 256, 256, 0, stream>>>(row_ptr, cursor, partials);
  k_scatter<<<(ET + 255) / 256, 256, 0, stream>>>(src, dst, cursor, adj);

  // layer 1 (input-space aggregation; no full h1 materialization)
  k_prep<<<1, 256, 0, stream>>>(W1, asrc1, adst1, AB);
  k_att1<<<(NT + 31) / 32, 256, 0, stream>>>(x, AB, es1, ed1);
  k_agg1<<<NT, 128, 0, stream>>>(row_ptr, adj, es1, ed1, x, W1, b1, h1o);

  // layer 2
  k_gemm2<<<(NT + 63) / 64, 256, 0, stream>>>(h1o, W2, asrc2, adst2, h2, es2, ed2);
  k_agg2<<<(NT + 3) / 4, 256, 0, stream>>>(row_ptr, adj, es2, ed2, h2, b2, h2o);

  // pool + classify
  k_pool2<<<GT, 256, 0, stream>>>(h2o, batch, Wc, bc, out);
}

// Round 6
// 478.563 us; speedup vs baseline: 2.8897x; 1.0461x over previous
//
#include <hip/hip_runtime.h>
#include <math.h>

#define NT 100000
#define ET 1600000
#define GT 128

typedef float f4 __attribute__((ext_vector_type(4)));

__device__ __forceinline__ float lrelu(float v) { return v > 0.0f ? v : 0.2f * v; }

// ---------------- CSR build ----------------
__global__ void k_count(const int* __restrict__ dst, int* __restrict__ counts) {
  int e = blockIdx.x * 256 + threadIdx.x;
  if (e < ET) atomicAdd(&counts[dst[e]], 1);
}

__global__ __launch_bounds__(256) void k_scan1(const int* __restrict__ counts,
                                               int* __restrict__ scanned,
                                               int* __restrict__ partials) {
  __shared__ int sh[256];
  int t = threadIdx.x;
  int base = blockIdx.x * 1024 + t * 4;
  int v[4];
#pragma unroll
  for (int i = 0; i < 4; ++i) v[i] = (base + i < NT) ? counts[base + i] : 0;
  int tsum = v[0] + v[1] + v[2] + v[3];
  sh[t] = tsum;
  __syncthreads();
  for (int off = 1; off < 256; off <<= 1) {
    int xv = (t >= off) ? sh[t - off] : 0;
    __syncthreads();
    sh[t] += xv;
    __syncthreads();
  }
  int ex = sh[t] - tsum;
#pragma unroll
  for (int i = 0; i < 4; ++i) {
    if (base + i < NT) scanned[base + i] = ex;
    ex += v[i];
  }
  if (t == 255) partials[blockIdx.x] = sh[255];
}

__global__ void k_scan2(int* partials) {
  if (threadIdx.x == 0) {
    int s = 0;
    for (int i = 0; i < 98; ++i) { int v = partials[i]; partials[i] = s; s += v; }
    partials[98] = s;
  }
}

__global__ void k_scan3(int* __restrict__ rp, int* __restrict__ cursor,
                        const int* __restrict__ partials) {
  int i = blockIdx.x * 256 + threadIdx.x;
  if (i < NT) {
    int v = rp[i] + partials[i >> 10];
    rp[i] = v;
    cursor[i] = v;
    if (i == 0) rp[NT] = ET;
  }
}

__global__ void k_scatter(const int* __restrict__ src, const int* __restrict__ dst,
                          int* __restrict__ cursor, int* __restrict__ adj) {
  int e = blockIdx.x * 256 + threadIdx.x;
  if (e < ET) {
    int pos = atomicAdd(&cursor[dst[e]], 1);
    adj[pos] = src[e];
  }
}

// ---------------- prep: AB[k][j] = sum_c W1[k][h*32+c] * a[h][c]  (j<4: src, j>=4: dst) ----------------
__global__ void k_prep(const float* __restrict__ W1, const float* __restrict__ as1,
                       const float* __restrict__ ad1, float* __restrict__ AB) {
  int t = threadIdx.x;  // 256
  int k = t >> 3, j = t & 7;
  const float* a = (j < 4) ? as1 : ad1;
  int h = j & 3;
  float s = 0.0f;
  for (int c = 0; c < 32; ++c) s += W1[k * 128 + h * 32 + c] * a[h * 32 + c];
  AB[t] = s;  // AB[k*8 + j]
}

// ---------------- att1: es1/ed1 = x @ AB (N x 32 x 8) ----------------
__global__ __launch_bounds__(256) void k_att1(const float* __restrict__ x, const float* __restrict__ AB,
                                              float* __restrict__ es, float* __restrict__ ed) {
  __shared__ float xsh[32 * 33];
  __shared__ float absh[256];
  int t = threadIdx.x;
  int n0 = blockIdx.x * 32;
  absh[t] = AB[t];
  for (int i = t; i < 1024; i += 256) {
    int ln = i >> 5, k = i & 31;
    int node = n0 + ln;
    xsh[ln * 33 + k] = (node < NT) ? x[node * 32 + k] : 0.0f;
  }
  __syncthreads();
  int ln = t >> 3, j = t & 7;
  int node = n0 + ln;
  if (node < NT) {
    float s = 0.0f;
#pragma unroll
    for (int k = 0; k < 32; ++k) s += xsh[ln * 33 + k] * absh[k * 8 + j];
    if (j < 4) es[node * 4 + j] = s;
    else ed[node * 4 + (j - 4)] = s;
  }
}

// ---------------- agg1f: fused layer-1 aggregation (input space) + layer-2 GEMM ----------------
// Wave-per-node, 4 nodes/block, wave-local sync only.
// y_h = sum_s alpha^h_s x[s]; o = elu(y@W1+b1); h2 = o@W2; es2/ed2 = h2 . a2
__global__ __launch_bounds__(256) void k_agg1f(
    const int* __restrict__ rp, const int* __restrict__ adj,
    const float* __restrict__ es, const float* __restrict__ ed,
    const float* __restrict__ x,
    const float* __restrict__ W1, const float* __restrict__ b1,
    const float* __restrict__ W2,
    const float* __restrict__ as2, const float* __restrict__ ad2,
    float* __restrict__ h2, float* __restrict__ es2, float* __restrict__ ed2) {
  __shared__ int sbuf_all[4][66];
  __shared__ f4 wbuf_all[4][66];
  __shared__ float ysh_all[4][132];
  __shared__ float osh_all[4][128];
  int wv = threadIdx.x >> 6, l = threadIdx.x & 63;
  int n = blockIdx.x * 4 + wv;
  if (n >= NT) return;
  int* sbuf = sbuf_all[wv];
  f4* wbufv = wbuf_all[wv];
  float* ysh = ysh_all[wv];
  float* osh = osh_all[wv];
  const f4* es4 = (const f4*)es;
  int rs = rp[n], re = rp[n + 1];
  int deg = re - rs;
  f4 edn = ((const f4*)ed)[n];
  f4 esn = es4[n];
  float edna[4], vs[4];
#pragma unroll
  for (int h = 0; h < 4; ++h) { edna[h] = edn[h]; vs[h] = lrelu(esn[h] + edn[h]); }
  int ep = l >> 5, c = l & 31;
  float acc[4] = {0.0f, 0.0f, 0.0f, 0.0f};

  if (deg <= 64) {
    float v[4];
    if (l < deg) {
      int s = adj[rs + l];
      sbuf[l] = s;
      f4 ev = es4[s];
#pragma unroll
      for (int h = 0; h < 4; ++h) v[h] = lrelu(ev[h] + edna[h]);
    } else {
#pragma unroll
      for (int h = 0; h < 4; ++h) v[h] = -1e30f;
    }
    float m[4];
#pragma unroll
    for (int h = 0; h < 4; ++h) m[h] = v[h];
#pragma unroll
    for (int off = 1; off <= 32; off <<= 1)
#pragma unroll
      for (int h = 0; h < 4; ++h) m[h] = fmaxf(m[h], __shfl_xor(m[h], off));
#pragma unroll
    for (int h = 0; h < 4; ++h) m[h] = fmaxf(m[h], vs[h]);
    float ex[4], d[4];
#pragma unroll
    for (int h = 0; h < 4; ++h) { ex[h] = (l < deg) ? __expf(v[h] - m[h]) : 0.0f; d[h] = ex[h]; }
#pragma unroll
    for (int off = 1; off <= 32; off <<= 1)
#pragma unroll
      for (int h = 0; h < 4; ++h) d[h] += __shfl_xor(d[h], off);
    float inv[4], wself[4];
#pragma unroll
    for (int h = 0; h < 4; ++h) {
      float sv = __expf(vs[h] - m[h]);
      inv[h] = 1.0f / (d[h] + sv);
      wself[h] = sv * inv[h];
    }
    if (l < deg) {
      f4 w4;
#pragma unroll
      for (int h = 0; h < 4; ++h) w4[h] = ex[h] * inv[h];
      wbufv[l] = w4;
    }
    if (l == 0) {
      sbuf[deg] = n;
      f4 w4;
#pragma unroll
      for (int h = 0; h < 4; ++h) w4[h] = wself[h];
      wbufv[deg] = w4;
    }
    __builtin_amdgcn_wave_barrier();
    for (int e = ep; e < deg + 1; e += 2) {
      float xv = x[sbuf[e] * 32 + c];
      f4 w4 = wbufv[e];
#pragma unroll
      for (int h = 0; h < 4; ++h) acc[h] += w4[h] * xv;
    }
  } else {
    // generic path (deg > 64, rare)
    float m[4], den[4];
#pragma unroll
    for (int h = 0; h < 4; ++h) { m[h] = -1e30f; den[h] = 0.0f; }
    for (int j = rs + l; j < re; j += 64) {
      int s = adj[j];
      f4 ev = es4[s];
#pragma unroll
      for (int h = 0; h < 4; ++h) {
        float v = lrelu(ev[h] + edna[h]);
        if (v > m[h]) { den[h] = den[h] * __expf(m[h] - v) + 1.0f; m[h] = v; }
        else den[h] += __expf(v - m[h]);
      }
    }
#pragma unroll
    for (int off = 1; off <= 32; off <<= 1) {
#pragma unroll
      for (int h = 0; h < 4; ++h) {
        float m2 = __shfl_xor(m[h], off), d2 = __shfl_xor(den[h], off);
        float mm = fmaxf(m[h], m2);
        den[h] = den[h] * __expf(m[h] - mm) + d2 * __expf(m2 - mm);
        m[h] = mm;
      }
    }
    float inv[4], wself[4];
#pragma unroll
    for (int h = 0; h < 4; ++h) {
      float mm = fmaxf(m[h], vs[h]);
      float dd = den[h] * __expf(m[h] - mm) + __expf(vs[h] - mm);
      m[h] = mm;
      inv[h] = 1.0f / dd;
      wself[h] = __expf(vs[h] - mm) * inv[h];
    }
    for (int base = rs; base < re; base += 64) {
      int cnt = min(64, re - base);
      if (l < cnt) {
        int s = adj[base + l];
        sbuf[l] = s;
        f4 ev = es4[s];
        f4 w4;
#pragma unroll
        for (int h = 0; h < 4; ++h) w4[h] = __expf(lrelu(ev[h] + edna[h]) - m[h]) * inv[h];
        wbufv[l] = w4;
      }
      __builtin_amdgcn_wave_barrier();
      for (int e = ep; e < cnt; e += 2) {
        float xv = x[sbuf[e] * 32 + c];
        f4 w4 = wbufv[e];
#pragma unroll
        for (int h = 0; h < 4; ++h) acc[h] += w4[h] * xv;
      }
      __builtin_amdgcn_wave_barrier();
    }
    if (ep == 0) {
      float xv = x[n * 32 + c];
#pragma unroll
      for (int h = 0; h < 4; ++h) acc[h] += wself[h] * xv;
    }
  }

  // merge halves -> y[h][c]
#pragma unroll
  for (int h = 0; h < 4; ++h) acc[h] += __shfl_xor(acc[h], 32);
  if (ep == 0) {
#pragma unroll
    for (int h = 0; h < 4; ++h) ysh[h * 33 + c] = acc[h];
  }
  __builtin_amdgcn_wave_barrier();

  // matvec1 + ELU: out channels t0=l, t1=l+64
  int h0 = l >> 5, h1 = h0 + 2;
  float o0 = b1[l], o1 = b1[l + 64];
#pragma unroll 8
  for (int k = 0; k < 32; ++k) {
    o0 += ysh[h0 * 33 + k] * W1[k * 128 + l];
    o1 += ysh[h1 * 33 + k] * W1[k * 128 + l + 64];
  }
  o0 = o0 > 0.0f ? o0 : __expf(o0) - 1.0f;
  o1 = o1 > 0.0f ? o1 : __expf(o1) - 1.0f;
  osh[l] = o0;
  osh[l + 64] = o1;
  __builtin_amdgcn_wave_barrier();

  // matvec2: h2[c] = sum_k osh[k]*W2[k*32+c]; split k into 2 halves by ep
  float p = 0.0f;
#pragma unroll 8
  for (int kk = 0; kk < 64; ++kk) {
    int k = ep * 64 + kk;
    p += osh[k] * W2[k * 32 + c];
  }
  p += __shfl_xor(p, 32);
  // attention logits for layer 2
  float psv = p * as2[c], pdv = p * ad2[c];
#pragma unroll
  for (int off = 1; off <= 16; off <<= 1) {
    psv += __shfl_xor(psv, off);
    pdv += __shfl_xor(pdv, off);
  }
  if (l == 0) { es2[n] = psv; ed2[n] = pdv; }
  if (ep == 0) h2[n * 32 + c] = p;
}

// ---------------- agg2: 1 wave per node, 4 nodes/block, wave-local ----------------
__global__ __launch_bounds__(256) void k_agg2(const int* __restrict__ rp, const int* __restrict__ adj,
                                              const float* __restrict__ es, const float* __restrict__ ed,
                                              const float* __restrict__ h, const float* __restrict__ b2,
                                              float* __restrict__ out) {
  __shared__ int sbuf_all[4][64];
  __shared__ float wbuf_all[4][64];
  int wv = threadIdx.x >> 6;
  int l = threadIdx.x & 63;
  int n = blockIdx.x * 4 + wv;
  if (n >= NT) return;
  int* sbuf = sbuf_all[wv];
  float* wbuf = wbuf_all[wv];
  int rs = rp[n], re = rp[n + 1];
  int deg = re - rs;
  float edst = ed[n];
  float vs = lrelu(es[n] + edst);
  int c = l & 31, half = l >> 5;

  if (deg <= 64) {
    float v = -1e30f;
    if (l < deg) {
      int s = adj[rs + l];
      sbuf[l] = s;
      v = lrelu(es[s] + edst);
    }
    float m = v;
#pragma unroll
    for (int off = 1; off <= 32; off <<= 1) m = fmaxf(m, __shfl_xor(m, off));
    m = fmaxf(m, vs);
    float ex = (l < deg) ? __expf(v - m) : 0.0f;
    float d = ex;
#pragma unroll
    for (int off = 1; off <= 32; off <<= 1) d += __shfl_xor(d, off);
    float inv = 1.0f / (d + __expf(vs - m));
    if (l < deg) wbuf[l] = ex * inv;
    __builtin_amdgcn_wave_barrier();
    float acc = (half == 0) ? __expf(vs - m) * inv * h[n * 32 + c] : 0.0f;
    for (int e = half; e < deg; e += 2) {
      acc += wbuf[e] * h[sbuf[e] * 32 + c];
    }
    acc += __shfl_xor(acc, 32);
    if (half == 0) {
      float o = acc + b2[c];
      out[n * 32 + c] = o > 0.0f ? o : __expf(o) - 1.0f;
    }
    return;
  }

  // generic path (rare)
  float m = -1e30f, den = 0.0f;
  for (int j = rs + l; j < re; j += 64) {
    float v = lrelu(es[adj[j]] + edst);
    if (v > m) { den = den * __expf(m - v) + 1.0f; m = v; }
    else den += __expf(v - m);
  }
#pragma unroll
  for (int off = 1; off <= 32; off <<= 1) {
    float m2 = __shfl_xor(m, off);
    float d2 = __shfl_xor(den, off);
    float mm = fmaxf(m, m2);
    den = den * __expf(m - mm) + d2 * __expf(m2 - mm);
    m = mm;
  }
  float mf = fmaxf(m, vs);
  float dd = den * __expf(m - mf) + __expf(vs - mf);
  float inv = 1.0f / dd;
  float acc = (half == 0) ? __expf(vs - mf) * inv * h[n * 32 + c] : 0.0f;
  for (int base = rs; base < re; base += 64) {
    int j = base + l;
    if (j < re) {
      int s = adj[j];
      sbuf[l] = s;
      wbuf[l] = __expf(lrelu(es[s] + edst) - mf) * inv;
    }
    __builtin_amdgcn_wave_barrier();
    int cnt = min(64, re - base);
    for (int e = half; e < cnt; e += 2) {
      acc += wbuf[e] * h[sbuf[e] * 32 + c];
    }
    __builtin_amdgcn_wave_barrier();
  }
  acc += __shfl_xor(acc, 32);
  if (half == 0) {
    float o = acc + b2[c];
    out[n * 32 + c] = o > 0.0f ? o : __expf(o) - 1.0f;
  }
}

// ---------------- pooling + classifier: one block per graph, zero atomics ----------------
__global__ __launch_bounds__(256) void k_pool2(const float* __restrict__ h, const int* __restrict__ batch,
                                               const float* __restrict__ Wc, const float* __restrict__ bc,
                                               float* __restrict__ out) {
  int g = blockIdx.x;
  int lo = 0, hi = NT;
  while (lo < hi) { int mid = (lo + hi) >> 1; if (batch[mid] < g) lo = mid + 1; else hi = mid; }
  int start = lo;
  hi = NT;
  while (lo < hi) { int mid = (lo + hi) >> 1; if (batch[mid] < g + 1) lo = mid + 1; else hi = mid; }
  int end = lo;

  int t = threadIdx.x, c = t & 31, r = t >> 5;
  float acc = 0.0f;
  for (int n = start + r; n < end; n += 8) acc += h[n * 32 + c];
  __shared__ float sh[256];
  sh[t] = acc;
  __syncthreads();
  if (r == 0) {
    float s = 0.0f;
#pragma unroll
    for (int i = 0; i < 8; ++i) s += sh[i * 32 + c];
    float cnt = (float)(end - start);
    float inv = 1.0f / fmaxf(cnt, 1.0f);
    float v = s * inv * Wc[c];
#pragma unroll
    for (int off = 16; off >= 1; off >>= 1) v += __shfl_xor(v, off);
    if (c == 0) out[g] = v + bc[0];
  }
}

extern "C" void kernel_launch(void* const* d_in, const int* in_sizes, int n_in,
                              void* d_out, int out_size, void* d_ws, size_t ws_size,
                              hipStream_t stream) {
  const float* x = (const float*)d_in[0];
  const int* ei = (const int*)d_in[1];
  const int* src = ei;
  const int* dst = ei + ET;
  const int* batch = (const int*)d_in[2];
  const float* W1 = (const float*)d_in[3];
  const float* asrc1 = (const float*)d_in[4];
  const float* adst1 = (const float*)d_in[5];
  const float* b1 = (const float*)d_in[6];
  const float* W2 = (const float*)d_in[7];
  const float* asrc2 = (const float*)d_in[8];
  const float* adst2 = (const float*)d_in[9];
  const float* b2 = (const float*)d_in[10];
  const float* Wc = (const float*)d_in[11];
  const float* bc = (const float*)d_in[12];
  float* out = (float*)d_out;
  char* ws = (char*)d_ws;

  int* row_ptr = (int*)(ws + 0);          // 400128
  int* cursor = (int*)(ws + 400128);      // 400000
  int* partials = (int*)(ws + 800256);    // 512
  float* AB = (float*)(ws + 800768);      // 1024
  int* adj = (int*)(ws + 801792);         // 6.4MB -> 7201792
  float* es1 = (float*)(ws + 7201792);    // 1.6MB  (16B aligned)
  float* ed1 = (float*)(ws + 8801792);    // 1.6MB  (16B aligned)
  float* es2 = (float*)(ws + 10401792);   // 400KB
  float* ed2 = (float*)(ws + 10801792);   // 400KB
  float* h2 = (float*)(ws + 11201792);    // 12.8MB -> 24001792
  float* h2o = (float*)(ws + 24001792);   // 12.8MB -> 36801792

  hipMemsetAsync(cursor, 0, NT * 4, stream);

  // CSR build (shared by both layers)
  k_count<<<(ET + 255) / 256, 256, 0, stream>>>(dst, cursor);
  k_scan1<<<98, 256, 0, stream>>>(cursor, row_ptr, partials);
  k_scan2<<<1, 64, 0, stream>>>(partials);
  k_scan3<<<(NT + 255) / 256, 256, 0, stream>>>(row_ptr, cursor, partials);
  k_scatter<<<(ET + 255) / 256, 256, 0, stream>>>(src, dst, cursor, adj);

  // layer 1 attention logits (tiny projection, no h1 materialization)
  k_prep<<<1, 256, 0, stream>>>(W1, asrc1, adst1, AB);
  k_att1<<<(NT + 31) / 32, 256, 0, stream>>>(x, AB, es1, ed1);

  // fused: layer-1 aggregate (input space) + layer-1 matvec + ELU + layer-2 GEMM + layer-2 logits
  k_agg1f<<<(NT + 3) / 4, 256, 0, stream>>>(row_ptr, adj, es1, ed1, x, W1, b1, W2,
                                            asrc2, adst2, h2, es2, ed2);

  // layer 2 aggregation
  k_agg2<<<(NT + 3) / 4, 256, 0, stream>>>(row_ptr, adj, es2, ed2, h2, b2, h2o);

  // pool + classify
  k_pool2<<<GT, 256, 0, stream>>>(h2o, batch, Wc, bc, out);
}

// Round 7
// 475.864 us; speedup vs baseline: 2.9061x; 1.0057x over previous
//
#include <hip/hip_runtime.h>
#include <math.h>

#define NT 100000
#define ET 1600000
#define GT 128

typedef float f4 __attribute__((ext_vector_type(4)));

__device__ __forceinline__ float lrelu(float v) { return v > 0.0f ? v : 0.2f * v; }
__device__ __forceinline__ float elu1(float v) { return v > 0.0f ? v : __expf(v) - 1.0f; }

// ---------------- CSR build ----------------
__global__ void k_count(const int* __restrict__ dst, int* __restrict__ counts) {
  int e = blockIdx.x * 256 + threadIdx.x;
  if (e < ET) atomicAdd(&counts[dst[e]], 1);
}

__global__ __launch_bounds__(256) void k_scan1(const int* __restrict__ counts,
                                               int* __restrict__ scanned,
                                               int* __restrict__ partials) {
  __shared__ int sh[256];
  int t = threadIdx.x;
  int base = blockIdx.x * 1024 + t * 4;
  int v[4];
#pragma unroll
  for (int i = 0; i < 4; ++i) v[i] = (base + i < NT) ? counts[base + i] : 0;
  int tsum = v[0] + v[1] + v[2] + v[3];
  sh[t] = tsum;
  __syncthreads();
  for (int off = 1; off < 256; off <<= 1) {
    int xv = (t >= off) ? sh[t - off] : 0;
    __syncthreads();
    sh[t] += xv;
    __syncthreads();
  }
  int ex = sh[t] - tsum;
#pragma unroll
  for (int i = 0; i < 4; ++i) {
    if (base + i < NT) scanned[base + i] = ex;
    ex += v[i];
  }
  if (t == 255) partials[blockIdx.x] = sh[255];
}

__global__ void k_scan2(int* partials) {
  if (threadIdx.x == 0) {
    int s = 0;
    for (int i = 0; i < 98; ++i) { int v = partials[i]; partials[i] = s; s += v; }
    partials[98] = s;
  }
}

__global__ void k_scan3(int* __restrict__ rp, int* __restrict__ cursor,
                        const int* __restrict__ partials) {
  int i = blockIdx.x * 256 + threadIdx.x;
  if (i < NT) {
    int v = rp[i] + partials[i >> 10];
    rp[i] = v;
    cursor[i] = v;
    if (i == 0) rp[NT] = ET;
  }
}

__global__ void k_scatter(const int* __restrict__ src, const int* __restrict__ dst,
                          int* __restrict__ cursor, int* __restrict__ adj) {
  int e = blockIdx.x * 256 + threadIdx.x;
  if (e < ET) {
    int pos = atomicAdd(&cursor[dst[e]], 1);
    adj[pos] = src[e];
  }
}

// ---------------- prep: AB[k][j] = sum_c W1[k][h*32+c] * a[h][c]  (j<4: src, j>=4: dst) ----------------
__global__ void k_prep(const float* __restrict__ W1, const float* __restrict__ as1,
                       const float* __restrict__ ad1, float* __restrict__ AB) {
  int t = threadIdx.x;  // 256
  int k = t >> 3, j = t & 7;
  const float* a = (j < 4) ? as1 : ad1;
  int h = j & 3;
  float s = 0.0f;
  for (int c = 0; c < 32; ++c) s += W1[k * 128 + h * 32 + c] * a[h * 32 + c];
  AB[t] = s;  // AB[k*8 + j]
}

// ---------------- att1: es1/ed1 = x @ AB (N x 32 x 8) ----------------
__global__ __launch_bounds__(256) void k_att1(const float* __restrict__ x, const float* __restrict__ AB,
                                              float* __restrict__ es, float* __restrict__ ed) {
  __shared__ float xsh[32 * 33];
  __shared__ float absh[256];
  int t = threadIdx.x;
  int n0 = blockIdx.x * 32;
  absh[t] = AB[t];
  for (int i = t; i < 1024; i += 256) {
    int ln = i >> 5, k = i & 31;
    int node = n0 + ln;
    xsh[ln * 33 + k] = (node < NT) ? x[node * 32 + k] : 0.0f;
  }
  __syncthreads();
  int ln = t >> 3, j = t & 7;
  int node = n0 + ln;
  if (node < NT) {
    float s = 0.0f;
#pragma unroll
    for (int k = 0; k < 32; ++k) s += xsh[ln * 33 + k] * absh[k * 8 + j];
    if (j < 4) es[node * 4 + j] = s;
    else ed[node * 4 + (j - 4)] = s;
  }
}

// ---------------- agg1f: fused L1 aggregate (input space) + L1 matvec + ELU + L2 GEMM + L2 logits ----------------
// Wave-per-node, 4 nodes/block, wave-local sync only. All hot loops b128.
__global__ __launch_bounds__(256) void k_agg1f(
    const int* __restrict__ rp, const int* __restrict__ adj,
    const float* __restrict__ es, const float* __restrict__ ed,
    const float* __restrict__ x,
    const float* __restrict__ W1, const float* __restrict__ b1,
    const float* __restrict__ W2,
    const float* __restrict__ as2, const float* __restrict__ ad2,
    float* __restrict__ h2, float* __restrict__ es2, float* __restrict__ ed2) {
  __shared__ int sbuf_all[4][66];
  __shared__ f4 wbuf_all[4][66];
  __shared__ float ysh_all[4][128];
  __shared__ float osh_all[4][128];
  int wv = threadIdx.x >> 6, l = threadIdx.x & 63;
  int n = blockIdx.x * 4 + wv;
  if (n >= NT) return;
  int* sbuf = sbuf_all[wv];
  f4* wbufv = wbuf_all[wv];
  float* ysh = ysh_all[wv];
  float* osh = osh_all[wv];
  const f4* es4 = (const f4*)es;
  int rs = rp[n], re = rp[n + 1];
  int deg = re - rs;
  f4 edn = ((const f4*)ed)[n];
  f4 esn = es4[n];
  float edna[4], vs[4];
#pragma unroll
  for (int h = 0; h < 4; ++h) { edna[h] = edn[h]; vs[h] = lrelu(esn[h] + edn[h]); }
  int eg = l >> 3, q = l & 7;  // edge-group, quarter-row
  f4 a0 = {0,0,0,0}, a1 = {0,0,0,0}, a2 = {0,0,0,0}, a3 = {0,0,0,0};

  if (deg <= 64) {
    float v[4];
    if (l < deg) {
      int s = adj[rs + l];
      sbuf[l] = s;
      f4 ev = es4[s];
#pragma unroll
      for (int h = 0; h < 4; ++h) v[h] = lrelu(ev[h] + edna[h]);
    } else {
#pragma unroll
      for (int h = 0; h < 4; ++h) v[h] = -1e30f;
    }
    float m[4];
#pragma unroll
    for (int h = 0; h < 4; ++h) m[h] = v[h];
#pragma unroll
    for (int off = 1; off <= 32; off <<= 1)
#pragma unroll
      for (int h = 0; h < 4; ++h) m[h] = fmaxf(m[h], __shfl_xor(m[h], off));
#pragma unroll
    for (int h = 0; h < 4; ++h) m[h] = fmaxf(m[h], vs[h]);
    float ex[4], d[4];
#pragma unroll
    for (int h = 0; h < 4; ++h) { ex[h] = (l < deg) ? __expf(v[h] - m[h]) : 0.0f; d[h] = ex[h]; }
#pragma unroll
    for (int off = 1; off <= 32; off <<= 1)
#pragma unroll
      for (int h = 0; h < 4; ++h) d[h] += __shfl_xor(d[h], off);
    float inv[4], wself[4];
#pragma unroll
    for (int h = 0; h < 4; ++h) {
      float sv = __expf(vs[h] - m[h]);
      inv[h] = 1.0f / (d[h] + sv);
      wself[h] = sv * inv[h];
    }
    if (l < deg) {
      f4 w4;
#pragma unroll
      for (int h = 0; h < 4; ++h) w4[h] = ex[h] * inv[h];
      wbufv[l] = w4;
    }
    if (l == 0) {
      sbuf[deg] = n;
      f4 w4;
#pragma unroll
      for (int h = 0; h < 4; ++h) w4[h] = wself[h];
      wbufv[deg] = w4;
    }
    __builtin_amdgcn_wave_barrier();
    // gather: 8 edge-groups x 8 lanes, each lane loads f4 of the row
    for (int e = eg; e <= deg; e += 8) {
      f4 xv = *(const f4*)&x[sbuf[e] * 32 + 4 * q];
      f4 w4 = wbufv[e];
      a0 += w4.x * xv; a1 += w4.y * xv; a2 += w4.z * xv; a3 += w4.w * xv;
    }
  } else {
    // generic path (deg > 64, rare)
    float m[4], den[4];
#pragma unroll
    for (int h = 0; h < 4; ++h) { m[h] = -1e30f; den[h] = 0.0f; }
    for (int j = rs + l; j < re; j += 64) {
      int s = adj[j];
      f4 ev = es4[s];
#pragma unroll
      for (int h = 0; h < 4; ++h) {
        float v = lrelu(ev[h] + edna[h]);
        if (v > m[h]) { den[h] = den[h] * __expf(m[h] - v) + 1.0f; m[h] = v; }
        else den[h] += __expf(v - m[h]);
      }
    }
#pragma unroll
    for (int off = 1; off <= 32; off <<= 1) {
#pragma unroll
      for (int h = 0; h < 4; ++h) {
        float m2 = __shfl_xor(m[h], off), d2 = __shfl_xor(den[h], off);
        float mm = fmaxf(m[h], m2);
        den[h] = den[h] * __expf(m[h] - mm) + d2 * __expf(m2 - mm);
        m[h] = mm;
      }
    }
    float inv[4], wself[4];
#pragma unroll
    for (int h = 0; h < 4; ++h) {
      float mm = fmaxf(m[h], vs[h]);
      float dd = den[h] * __expf(m[h] - mm) + __expf(vs[h] - mm);
      m[h] = mm;
      inv[h] = 1.0f / dd;
      wself[h] = __expf(vs[h] - mm) * inv[h];
    }
    for (int base = rs; base < re; base += 64) {
      int cnt = min(64, re - base);
      if (l < cnt) {
        int s = adj[base + l];
        sbuf[l] = s;
        f4 ev = es4[s];
        f4 w4;
#pragma unroll
        for (int h = 0; h < 4; ++h) w4[h] = __expf(lrelu(ev[h] + edna[h]) - m[h]) * inv[h];
        wbufv[l] = w4;
      }
      __builtin_amdgcn_wave_barrier();
      for (int e = eg; e < cnt; e += 8) {
        f4 xv = *(const f4*)&x[sbuf[e] * 32 + 4 * q];
        f4 w4 = wbufv[e];
        a0 += w4.x * xv; a1 += w4.y * xv; a2 += w4.z * xv; a3 += w4.w * xv;
      }
      __builtin_amdgcn_wave_barrier();
    }
    if (eg == 0) {
      f4 xv = *(const f4*)&x[n * 32 + 4 * q];
      a0 += wself[0] * xv; a1 += wself[1] * xv; a2 += wself[2] * xv; a3 += wself[3] * xv;
    }
  }

  // reduce across edge-groups (xor 8,16,32)
#pragma unroll
  for (int off = 8; off <= 32; off <<= 1) {
#pragma unroll
    for (int cc = 0; cc < 4; ++cc) {
      a0[cc] += __shfl_xor(a0[cc], off);
      a1[cc] += __shfl_xor(a1[cc], off);
      a2[cc] += __shfl_xor(a2[cc], off);
      a3[cc] += __shfl_xor(a3[cc], off);
    }
  }
  if (eg == 0) {
    *(f4*)&ysh[0 * 32 + 4 * q] = a0;
    *(f4*)&ysh[1 * 32 + 4 * q] = a1;
    *(f4*)&ysh[2 * 32 + 4 * q] = a2;
    *(f4*)&ysh[3 * 32 + 4 * q] = a3;
  }
  __builtin_amdgcn_wave_barrier();

  // matvec1 + ELU: lane owns 4 contiguous out-channels; k split in halves across lane pairs
  int cl = l & 31, kh = l >> 5;
  int ch = cl * 4, hh = cl >> 3;
  f4 o = {0,0,0,0};
#pragma unroll
  for (int kk = 0; kk < 16; ++kk) {
    int k = kh * 16 + kk;
    float yv = ysh[hh * 32 + k];
    o += yv * *(const f4*)&W1[k * 128 + ch];
  }
#pragma unroll
  for (int cc = 0; cc < 4; ++cc) o[cc] += __shfl_xor(o[cc], 32);
  if (kh == 0) {
    f4 ob = *(const f4*)&b1[ch];
    o += ob;
#pragma unroll
    for (int cc = 0; cc < 4; ++cc) o[cc] = elu1(o[cc]);
    *(f4*)&osh[ch] = o;
  }
  __builtin_amdgcn_wave_barrier();

  // matvec2: h2[c] = sum_k osh[k]*W2[k*32+c]; lane owns 4 channels x 16-k group
  int c4 = q * 4;
  f4 p = {0,0,0,0};
#pragma unroll
  for (int kk = 0; kk < 16; ++kk) {
    int k = eg * 16 + kk;
    p += osh[k] * *(const f4*)&W2[k * 32 + c4];
  }
#pragma unroll
  for (int off = 8; off <= 32; off <<= 1)
#pragma unroll
    for (int cc = 0; cc < 4; ++cc) p[cc] += __shfl_xor(p[cc], off);

  float ps = 0.0f, pd = 0.0f;
  if (eg == 0) {
    *(f4*)&h2[n * 32 + c4] = p;
    f4 av = *(const f4*)&as2[c4];
    f4 dv = *(const f4*)&ad2[c4];
    ps = p.x * av.x + p.y * av.y + p.z * av.z + p.w * av.w;
    pd = p.x * dv.x + p.y * dv.y + p.z * dv.z + p.w * dv.w;
  }
#pragma unroll
  for (int off = 1; off <= 4; off <<= 1) {
    ps += __shfl_xor(ps, off);
    pd += __shfl_xor(pd, off);
  }
  if (l == 0) { es2[n] = ps; ed2[n] = pd; }
}

// ---------------- agg2: wave-per-node, b128 gather ----------------
__global__ __launch_bounds__(256) void k_agg2(const int* __restrict__ rp, const int* __restrict__ adj,
                                              const float* __restrict__ es, const float* __restrict__ ed,
                                              const float* __restrict__ h, const float* __restrict__ b2,
                                              float* __restrict__ out) {
  __shared__ int sbuf_all[4][66];
  __shared__ float wbuf_all[4][66];
  int wv = threadIdx.x >> 6;
  int l = threadIdx.x & 63;
  int n = blockIdx.x * 4 + wv;
  if (n >= NT) return;
  int* sbuf = sbuf_all[wv];
  float* wbuf = wbuf_all[wv];
  int rs = rp[n], re = rp[n + 1];
  int deg = re - rs;
  float edst = ed[n];
  float vs = lrelu(es[n] + edst);
  int eg = l >> 3, q = l & 7;
  f4 acc = {0,0,0,0};

  if (deg <= 64) {
    float v = -1e30f;
    if (l < deg) {
      int s = adj[rs + l];
      sbuf[l] = s;
      v = lrelu(es[s] + edst);
    }
    float m = v;
#pragma unroll
    for (int off = 1; off <= 32; off <<= 1) m = fmaxf(m, __shfl_xor(m, off));
    m = fmaxf(m, vs);
    float ex = (l < deg) ? __expf(v - m) : 0.0f;
    float d = ex;
#pragma unroll
    for (int off = 1; off <= 32; off <<= 1) d += __shfl_xor(d, off);
    float sv = __expf(vs - m);
    float inv = 1.0f / (d + sv);
    if (l < deg) wbuf[l] = ex * inv;
    if (l == 0) { sbuf[deg] = n; wbuf[deg] = sv * inv; }
    __builtin_amdgcn_wave_barrier();
    for (int e = eg; e <= deg; e += 8) {
      acc += wbuf[e] * *(const f4*)&h[sbuf[e] * 32 + 4 * q];
    }
  } else {
    // generic path (rare)
    float m = -1e30f, den = 0.0f;
    for (int j = rs + l; j < re; j += 64) {
      float v = lrelu(es[adj[j]] + edst);
      if (v > m) { den = den * __expf(m - v) + 1.0f; m = v; }
      else den += __expf(v - m);
    }
#pragma unroll
    for (int off = 1; off <= 32; off <<= 1) {
      float m2 = __shfl_xor(m, off);
      float d2 = __shfl_xor(den, off);
      float mm = fmaxf(m, m2);
      den = den * __expf(m - mm) + d2 * __expf(m2 - mm);
      m = mm;
    }
    float mf = fmaxf(m, vs);
    float dd = den * __expf(m - mf) + __expf(vs - mf);
    float inv = 1.0f / dd;
    float wself = __expf(vs - mf) * inv;
    for (int base = rs; base < re; base += 64) {
      int cnt = min(64, re - base);
      if (l < cnt) {
        int s = adj[base + l];
        sbuf[l] = s;
        wbuf[l] = __expf(lrelu(es[s] + edst) - mf) * inv;
      }
      __builtin_amdgcn_wave_barrier();
      for (int e = eg; e < cnt; e += 8) {
        acc += wbuf[e] * *(const f4*)&h[sbuf[e] * 32 + 4 * q];
      }
      __builtin_amdgcn_wave_barrier();
    }
    if (eg == 0) acc += wself * *(const f4*)&h[n * 32 + 4 * q];
  }

#pragma unroll
  for (int off = 8; off <= 32; off <<= 1)
#pragma unroll
    for (int cc = 0; cc < 4; ++cc) acc[cc] += __shfl_xor(acc[cc], off);
  if (eg == 0) {
    f4 o = acc + *(const f4*)&b2[4 * q];
#pragma unroll
    for (int cc = 0; cc < 4; ++cc) o[cc] = elu1(o[cc]);
    *(f4*)&out[n * 32 + 4 * q] = o;
  }
}

// ---------------- pooling + classifier: one block per graph, zero atomics ----------------
__global__ __launch_bounds__(256) void k_pool2(const float* __restrict__ h, const int* __restrict__ batch,
                                               const float* __restrict__ Wc, const float* __restrict__ bc,
                                               float* __restrict__ out) {
  int g = blockIdx.x;
  int lo = 0, hi = NT;
  while (lo < hi) { int mid = (lo + hi) >> 1; if (batch[mid] < g) lo = mid + 1; else hi = mid; }
  int start = lo;
  hi = NT;
  while (lo < hi) { int mid = (lo + hi) >> 1; if (batch[mid] < g + 1) lo = mid + 1; else hi = mid; }
  int end = lo;

  int t = threadIdx.x, c = t & 31, r = t >> 5;
  float acc = 0.0f;
  for (int n = start + r; n < end; n += 8) acc += h[n * 32 + c];
  __shared__ float sh[256];
  sh[t] = acc;
  __syncthreads();
  if (r == 0) {
    float s = 0.0f;
#pragma unroll
    for (int i = 0; i < 8; ++i) s += sh[i * 32 + c];
    float cnt = (float)(end - start);
    float inv = 1.0f / fmaxf(cnt, 1.0f);
    float v = s * inv * Wc[c];
#pragma unroll
    for (int off = 16; off >= 1; off >>= 1) v += __shfl_xor(v, off);
    if (c == 0) out[g] = v + bc[0];
  }
}

extern "C" void kernel_launch(void* const* d_in, const int* in_sizes, int n_in,
                              void* d_out, int out_size, void* d_ws, size_t ws_size,
                              hipStream_t stream) {
  const float* x = (const float*)d_in[0];
  const int* ei = (const int*)d_in[1];
  const int* src = ei;
  const int* dst = ei + ET;
  const int* batch = (const int*)d_in[2];
  const float* W1 = (const float*)d_in[3];
  const float* asrc1 = (const float*)d_in[4];
  const float* adst1 = (const float*)d_in[5];
  const float* b1 = (const float*)d_in[6];
  const float* W2 = (const float*)d_in[7];
  const float* asrc2 = (const float*)d_in[8];
  const float* adst2 = (const float*)d_in[9];
  const float* b2 = (const float*)d_in[10];
  const float* Wc = (const float*)d_in[11];
  const float* bc = (const float*)d_in[12];
  float* out = (float*)d_out;
  char* ws = (char*)d_ws;

  int* row_ptr = (int*)(ws + 0);          // 400128
  int* cursor = (int*)(ws + 400128);      // 400000
  int* partials = (int*)(ws + 800256);    // 512
  float* AB = (float*)(ws + 800768);      // 1024
  int* adj = (int*)(ws + 801792);         // 6.4MB -> 7201792
  float* es1 = (float*)(ws + 7201792);    // 1.6MB  (16B aligned)
  float* ed1 = (float*)(ws + 8801792);    // 1.6MB  (16B aligned)
  float* es2 = (float*)(ws + 10401792);   // 400KB
  float* ed2 = (float*)(ws + 10801792);   // 400KB
  float* h2 = (float*)(ws + 11201792);    // 12.8MB -> 24001792
  float* h2o = (float*)(ws + 24001792);   // 12.8MB -> 36801792

  hipMemsetAsync(cursor, 0, NT * 4, stream);

  // CSR build (shared by both layers)
  k_count<<<(ET + 255) / 256, 256, 0, stream>>>(dst, cursor);
  k_scan1<<<98, 256, 0, stream>>>(cursor, row_ptr, partials);
  k_scan2<<<1, 64, 0, stream>>>(partials);
  k_scan3<<<(NT + 255) / 256, 256, 0, stream>>>(row_ptr, cursor, partials);
  k_scatter<<<(ET + 255) / 256, 256, 0, stream>>>(src, dst, cursor, adj);

  // layer 1 attention logits (tiny projection, no h1 materialization)
  k_prep<<<1, 256, 0, stream>>>(W1, asrc1, adst1, AB);
  k_att1<<<(NT + 31) / 32, 256, 0, stream>>>(x, AB, es1, ed1);

  // fused: L1 aggregate (input space) + L1 matvec + ELU + L2 GEMM + L2 logits
  k_agg1f<<<(NT + 3) / 4, 256, 0, stream>>>(row_ptr, adj, es1, ed1, x, W1, b1, W2,
                                            asrc2, adst2, h2, es2, ed2);

  // layer 2 aggregation
  k_agg2<<<(NT + 3) / 4, 256, 0, stream>>>(row_ptr, adj, es2, ed2, h2, b2, h2o);

  // pool + classify
  k_pool2<<<GT, 256, 0, stream>>>(h2o, batch, Wc, bc, out);
}